// Round 1
// baseline (320.454 us; speedup 1.0000x reference)
//
#include <hip/hip_runtime.h>
#include <math.h>

#define L_LEN 2001
#define CCH 672           // positions per chunk (3 chunks cover 2016 >= 2001)
#define XR  704           // xs / y1 records per chunk (CCH + 32)
#define NTB 43            // conv1 tiles per chunk (produce y1 records [0,688))
#define NTC 42            // conv2 tiles per chunk (CCH/16 output positions)

typedef __attribute__((ext_vector_type(8))) short bf16x8;
typedef __attribute__((ext_vector_type(4))) float f32x4;
#if __has_builtin(__builtin_amdgcn_cvt_pk_bf16_f32)
typedef __attribute__((ext_vector_type(2))) __bf16 bf16x2_t;
#endif

union FragU { unsigned u[4]; uint2 u2[2]; uint4 u4; bf16x8 v; };

__device__ __forceinline__ unsigned short f2bf(float f) {
    unsigned u = __builtin_bit_cast(unsigned, f);
    u += 0x7fffu + ((u >> 16) & 1u);
    return (unsigned short)(u >> 16);
}
// pack two fp32 -> bf16 pair (RNE), hi<<16 | lo
__device__ __forceinline__ unsigned bfpack(float lo, float hi) {
#if __has_builtin(__builtin_amdgcn_cvt_pk_bf16_f32)
    bf16x2_t r = __builtin_amdgcn_cvt_pk_bf16_f32(lo, hi);   // S0 -> [15:0]
    return __builtin_bit_cast(unsigned, r);
#else
    unsigned ul = __builtin_bit_cast(unsigned, lo);
    unsigned uh = __builtin_bit_cast(unsigned, hi);
    ul += 0x7fffu + ((ul >> 16) & 1u);
    uh += 0x7fffu + ((uh >> 16) & 1u);
    return __builtin_amdgcn_perm(uh, ul, 0x07060302);
#endif
}
__device__ __forceinline__ float fast_rcp(float x) { return __builtin_amdgcn_rcpf(x); }
__device__ __forceinline__ float fexp2(float x) {
#if __has_builtin(__builtin_amdgcn_exp2f)
    return __builtin_amdgcn_exp2f(x);
#else
    return __expf(x * 0.69314718f);
#endif
}

// 3-chunk pipeline: LDS 17.2 KB/block -> 8 blocks/CU (32 waves = 100% occupancy
// ceiling), vs the 2-chunk variant's 25.5 KB -> 6 blocks/CU (58% measured).
__global__ __launch_bounds__(256, 8)
void taylor_cnn_v8_mfma(const float* __restrict__ phase, const float* __restrict__ primary,
                        const float* __restrict__ secondary, const float* __restrict__ oddeven,
                        const float* __restrict__ pA, const float* __restrict__ pBp,
                        const float* __restrict__ pT0,
                        const float* __restrict__ bng, const float* __restrict__ bnb,
                        const float* __restrict__ bnm, const float* __restrict__ bnv,
                        const float* __restrict__ w1, const float* __restrict__ b1,
                        const float* __restrict__ w2, const float* __restrict__ b2,
                        const float* __restrict__ fcw, const float* __restrict__ fcb,
                        float* __restrict__ out, int nrows)
{
    // xs: position-major, 4 ch bf16 (8 B/record). record m <-> position c0 + m - 16
    __shared__ __align__(16) unsigned int xs_i[XR * 2];   // 5.6 KB
    // y1: position-major, 8 ch bf16 (16 B/record). record q <-> position c0 + q - 8
    __shared__ __align__(16) unsigned int y1_i[XR * 4];   // 11.3 KB
    __shared__ float redA[4][16];
    __shared__ float redB[4][3];

    const int tid = threadIdx.x;
    const int row = blockIdx.x;
    const long base = (long)row * L_LEN;
    (void)nrows;

    const int lane = tid & 63;
    const int wid  = tid >> 6;
    const int n    = lane & 15;     // MFMA column (position in tile)
    const int quad = lane >> 4;     // MFMA k-block / D row-quad

    const float A  = pA[0];
    const float Bp = pBp[0];
    const float t0 = pT0[0];
    const float A_abs = fabsf(A) + 1e-8f;
    const float rAabs = 1.0f / A_abs;
    const float nBp  = -Bp;
    const float cExp = -72.134766f * rAabs;   // -50*log2(e)*rAabs: exp(-50*dn)=exp2(cExp*depth)

    float inv1, inv2, inv3, gInv0, off0, off1, off2, off3;
    {
        float iv0 = bng[0] / sqrtf(bnv[0] + 1e-5f);
        float iv1 = bng[1] / sqrtf(bnv[1] + 1e-5f);
        float iv2 = bng[2] / sqrtf(bnv[2] + 1e-5f);
        float iv3 = bng[3] / sqrtf(bnv[3] + 1e-5f);
        gInv0 = -A * iv0;                     // gate = relu(1-Bp*d^2); x0 = gate*(-A*iv0)+off0
        inv1 = iv1; inv2 = iv2; inv3 = iv3;
        off0 = bnb[0] - bnm[0] * iv0;
        off1 = bnb[1] - bnm[1] * iv1;
        off2 = bnb[2] - bnm[2] * iv2;
        off3 = bnb[3] - bnm[3] * iv3;
    }

    // ---- per-lane weight fragments ----
    bf16x8 a1;
#pragma unroll
    for (int jp = 0; jp < 8; ++jp) {
        int j = quad + 4 * (jp >> 2);
        int c = jp & 3;
        float v = (n < 8 && j < 7) ? w1[(n * 4 + c) * 7 + j] : 0.0f;
        a1[jp] = (short)f2bf(v);
    }
    bf16x8 a20, a21;
#pragma unroll
    for (int jp = 0; jp < 8; ++jp) {
        float v0 = w2[(n * 8 + jp) * 5 + quad];
        float v1 = (quad + 4 < 5) ? w2[(n * 8 + jp) * 5 + quad + 4] : 0.0f;
        a20[jp] = (short)f2bf(v0);
        a21[jp] = (short)f2bf(v1);
    }
    f32x4 cb1, cb2;   // bias seeded into MFMA C operand
#pragma unroll
    for (int r = 0; r < 4; ++r) {
        cb1[r] = b1[(quad * 4 + r) & 7];
        cb2[r] = b2[quad * 4 + r];
    }

    float s_ing = 0.0f, s_fb = 0.0f;
    float m0 = 0.f, m1 = 0.f, m2 = 0.f, m3 = 0.f;

    // trapz AUC samples early (scattered fp32 loads; overlap their latency)
    float s_auc = 0.0f;
    if (tid < 200) {
        float pos = (float)tid * (2000.0f / 199.0f);
        int i0 = (int)pos;
        if (i0 > 2000) i0 = 2000;
        int i1 = (i0 + 1 < L_LEN) ? i0 + 1 : 2000;
        float w  = pos - (float)i0;
        float d0 = fmaxf(-primary[base + i0], 0.f);
        float d1 = fmaxf(-primary[base + i1], 0.f);
        float v  = d0 * (1.0f - w) + d1 * w;
        float wt = (tid == 0 || tid == 199) ? 0.5f : 1.0f;
        s_auc = v * wt;
    }

    // ---- stage A record processor ----
    auto aRec = [&](int m, int p, bool chk) {
        bool valid = true, core = true;
        int pc = p;
        if (chk) {
            valid = ((unsigned)p < (unsigned)L_LEN);
            core  = valid && (m >= 16) && (m < 16 + CCH);
            pc = min(max(p, 0), L_LEN - 1);
        }
        float ph = phase[base + pc];
        float pf = primary[base + pc];
        float sf = secondary[base + pc];
        float oe = oddeven[base + pc];
        float dd = ph - t0;
        float g  = fmaxf(fmaf(dd * dd, nBp, 1.0f), 0.0f);
        float x0 = fmaf(g,  gInv0, off0);
        float x1 = fmaf(pf, inv1, off1);
        float x2 = fmaf(sf, inv2, off2);
        float x3 = fmaf(oe, inv3, off3);
        unsigned d0 = bfpack(x0, x1);
        unsigned d1 = bfpack(x2, x3);
        if (chk && !valid) { d0 = 0u; d1 = 0u; }
        *(uint2*)&xs_i[2 * m] = make_uint2(d0, d1);
        // soft-mask features (total==1+1e-8 -> 1.0f exactly in fp32; skip the division)
        float depth = fmaxf(-pf, 0.0f);
        float e   = fexp2(depth * cExp);                    // exp(-50*dn)
        float dip = fast_rcp(fmaf(e, 148.413159f, 1.0f));   // sigm(50(dn-0.1))
        float fb  = fast_rcp(fmaf(e, 2.35385267e17f, 1.0f));// sigm(50(dn-0.8))
        float ing = dip - fb;
        if (chk && !core) { ing = 0.f; fb = 0.f; }
        s_ing += ing;
        s_fb  += fb;
    };

    // per chunk: XR = 704 records; m = tid, tid+256, tid+512(<192)
    auto stageA = [&](int c0) {
        const int pb = c0 - 16;
        aRec(tid,       pb + tid,       true);    // m<16 straddle / core mask
        aRec(tid + 256, pb + tid + 256, false);   // interior, always valid+core
        if (tid < 192) aRec(tid + 512, pb + tid + 512, true);  // tail: core split / hi bound
    };

    // ---- stage B: conv1 via MFMA -> y1 ----
    // checks applied on tile t if (t == tLo || t >= tFrom) -- wave-uniform branch
    auto stageB = [&](int c0, int tLo, int tFrom) {
        for (int t = wid; t < NTB; t += 4) {
            int qb = 16 * t + n + quad + 5;
            FragU bu;
            bu.u2[0] = *(const uint2*)&xs_i[2 * qb];
            bu.u2[1] = *(const uint2*)&xs_i[2 * (qb + 4)];
            f32x4 d = __builtin_amdgcn_mfma_f32_16x16x32_bf16(a1, bu.v, cb1, 0, 0, 0);
            if (lane < 32) {                      // D rows 0..7 hold the 8 oc
                int q = 16 * t + n;
                unsigned w0, w1_;
                if (t == tLo || t >= tFrom) {     // wave-uniform branch
                    int p = c0 - 8 + q;
                    bool ok = ((unsigned)p < (unsigned)L_LEN);
                    w0  = ok ? bfpack(fmaxf(d[0], 0.f), fmaxf(d[1], 0.f)) : 0u;
                    w1_ = ok ? bfpack(fmaxf(d[2], 0.f), fmaxf(d[3], 0.f)) : 0u;
                } else {
                    w0  = bfpack(fmaxf(d[0], 0.f), fmaxf(d[1], 0.f));
                    w1_ = bfpack(fmaxf(d[2], 0.f), fmaxf(d[3], 0.f));
                }
                *(uint2*)&y1_i[4 * q + 2 * quad] = make_uint2(w0, w1_);
            }
        }
    };

    // ---- stage C: conv2 via MFMA, accumulate channel sums ----
    // maskT: tile whose outputs straddle position 2000 (only n==0 valid)
    auto stageC = [&](int maskT) {
        for (int t = wid; t < NTC; t += 4) {
            int q = 16 * t + n + quad + 6;
            FragU u0, u1;
            u0.u4 = *(const uint4*)&y1_i[4 * q];
            u1.u4 = *(const uint4*)&y1_i[4 * (q + 4)];
            f32x4 d = __builtin_amdgcn_mfma_f32_16x16x32_bf16(a20, u0.v, cb2, 0, 0, 0);
            d = __builtin_amdgcn_mfma_f32_16x16x32_bf16(a21, u1.v, d, 0, 0, 0);
            if (t == maskT) {                     // outputs 2000..2015: only n==0 valid
                float msk = (n == 0) ? 1.0f : 0.0f;
                m0 = fmaf(fmaxf(d[0], 0.f), msk, m0);
                m1 = fmaf(fmaxf(d[1], 0.f), msk, m1);
                m2 = fmaf(fmaxf(d[2], 0.f), msk, m2);
                m3 = fmaf(fmaxf(d[3], 0.f), msk, m3);
            } else {
                m0 += fmaxf(d[0], 0.f);
                m1 += fmaxf(d[1], 0.f);
                m2 += fmaxf(d[2], 0.f);
                m3 += fmaxf(d[3], 0.f);
            }
        }
    };

    // ---- pipeline: A0 | B0 | {A1,C0} | B1 | {A2,C1} | B2 | C2 ----
    stageA(0);
    __syncthreads();           // xs(0) ready
    stageB(0, 0, 99);          // low straddle at t=0
    __syncthreads();           // y1(0) ready; xs free
    stageA(CCH);               // xs(1) write overlaps C0's y1 reads (disjoint)
    stageC(-1);
    __syncthreads();           // xs(1) ready; y1 free
    stageB(CCH, -1, 99);       // interior chunk: no straddle
    __syncthreads();           // y1(1) ready; xs free
    stageA(2 * CCH);
    stageC(-1);
    __syncthreads();           // xs(2) ready; y1 free
    stageB(2 * CCH, -1, 41);   // hi straddle from t=41 (t=41 partial, t=42 all-invalid)
    __syncthreads();           // y1(2) ready
    stageC(41);                // outputs 2000+n at t=41: mask to n==0

    // ---- reductions ----
#pragma unroll
    for (int dlt = 8; dlt >= 1; dlt >>= 1) {
        m0 += __shfl_xor(m0, dlt);
        m1 += __shfl_xor(m1, dlt);
        m2 += __shfl_xor(m2, dlt);
        m3 += __shfl_xor(m3, dlt);
    }
    if ((lane & 15) == 0) {
        redA[wid][quad * 4 + 0] = m0;
        redA[wid][quad * 4 + 1] = m1;
        redA[wid][quad * 4 + 2] = m2;
        redA[wid][quad * 4 + 3] = m3;
    }
#pragma unroll
    for (int dlt = 32; dlt >= 1; dlt >>= 1) {
        s_ing += __shfl_xor(s_ing, dlt);
        s_fb  += __shfl_xor(s_fb,  dlt);
        s_auc += __shfl_xor(s_auc, dlt);
    }
    if (lane == 0) {
        redB[wid][0] = s_ing;
        redB[wid][1] = s_fb;
        redB[wid][2] = s_auc;
    }
    __syncthreads();

    if (tid == 0) {
        float logit = fcb[0];
#pragma unroll
        for (int oc = 0; oc < 16; ++oc) {
            float s = redA[0][oc] + redA[1][oc] + redA[2][oc] + redA[3][oc];
            logit += (s / 2001.0f) * fcw[oc];
        }
        float Sing = redB[0][0] + redB[1][0] + redB[2][0] + redB[3][0];
        float Sfb  = redB[0][1] + redB[1][1] + redB[2][1] + redB[3][1];
        float Sauc = redB[0][2] + redB[1][2] + redB[2][2] + redB[3][2];

        float auc_raw  = (float)(2.0 / 199.0) * Sauc;
        float auc_norm = auc_raw / A_abs;
        float m_ing = Sing / 2001.0f;
        float m_fb  = Sfb  / 2001.0f;
        float t14   = (Sing + Sfb) / 2001.0f + 1e-8f;
        float t12   = m_ing / t14;

        logit += Bp       * fcw[16]
               + auc_raw  * fcw[17]
               + auc_norm * fcw[18]
               + t12      * fcw[19]
               + m_fb     * fcw[20];

        out[row] = 1.0f / (1.0f + expf(-logit));
    }
}

extern "C" void kernel_launch(void* const* d_in, const int* in_sizes, int n_in,
                              void* d_out, int out_size, void* d_ws, size_t ws_size,
                              hipStream_t stream) {
    const float* phase     = (const float*)d_in[0];
    const float* primary   = (const float*)d_in[1];
    const float* secondary = (const float*)d_in[2];
    const float* oddeven   = (const float*)d_in[3];
    const float* pA        = (const float*)d_in[4];
    const float* pBp       = (const float*)d_in[5];
    const float* pT0       = (const float*)d_in[6];
    const float* bng       = (const float*)d_in[7];
    const float* bnb       = (const float*)d_in[8];
    const float* bnm       = (const float*)d_in[9];
    const float* bnv       = (const float*)d_in[10];
    const float* w1        = (const float*)d_in[11];
    const float* b1        = (const float*)d_in[12];
    const float* w2        = (const float*)d_in[13];
    const float* b2        = (const float*)d_in[14];
    const float* fcw       = (const float*)d_in[15];
    const float* fcb       = (const float*)d_in[16];
    float* out = (float*)d_out;

    int nrows = in_sizes[0] / L_LEN;   // 8192
    dim3 grid(nrows), block(256);
    hipLaunchKernelGGL(taylor_cnn_v8_mfma, grid, block, 0, stream,
                       phase, primary, secondary, oddeven, pA, pBp, pT0,
                       bng, bnb, bnm, bnv, w1, b1, w2, b2, fcw, fcb, out, nrows);
}

// Round 2
// 309.062 us; speedup vs baseline: 1.0369x; 1.0369x over previous
//
#include <hip/hip_runtime.h>
#include <math.h>

#define L_LEN 2001
#define CCH 672           // positions per chunk (3 chunks cover 2016 >= 2001)
#define XR  704           // xs / y1 records per chunk (CCH + 32)
#define NTB 43            // conv1 tiles per chunk (produce y1 records [0,688))
#define NTC 42            // conv2 tiles per chunk (CCH/16 output positions)

typedef __attribute__((ext_vector_type(8))) short bf16x8;
typedef __attribute__((ext_vector_type(4))) float f32x4;
#if __has_builtin(__builtin_amdgcn_cvt_pk_bf16_f32)
typedef __attribute__((ext_vector_type(2))) __bf16 bf16x2_t;
#endif

union FragU { unsigned u[4]; uint2 u2[2]; uint4 u4; bf16x8 v; };

__device__ __forceinline__ unsigned short f2bf(float f) {
    unsigned u = __builtin_bit_cast(unsigned, f);
    u += 0x7fffu + ((u >> 16) & 1u);
    return (unsigned short)(u >> 16);
}
// pack two fp32 -> bf16 pair (RNE), hi<<16 | lo
__device__ __forceinline__ unsigned bfpack(float lo, float hi) {
#if __has_builtin(__builtin_amdgcn_cvt_pk_bf16_f32)
    bf16x2_t r = __builtin_amdgcn_cvt_pk_bf16_f32(lo, hi);   // S0 -> [15:0]
    return __builtin_bit_cast(unsigned, r);
#else
    unsigned ul = __builtin_bit_cast(unsigned, lo);
    unsigned uh = __builtin_bit_cast(unsigned, hi);
    ul += 0x7fffu + ((ul >> 16) & 1u);
    uh += 0x7fffu + ((uh >> 16) & 1u);
    return __builtin_amdgcn_perm(uh, ul, 0x07060302);
#endif
}
__device__ __forceinline__ float fast_rcp(float x) { return __builtin_amdgcn_rcpf(x); }
__device__ __forceinline__ float fexp2(float x) {
#if __has_builtin(__builtin_amdgcn_exp2f)
    return __builtin_amdgcn_exp2f(x);
#else
    return __expf(x * 0.69314718f);
#endif
}

// 3-chunk pipeline: LDS 17.4 KB/block -> 8 blocks/CU by LDS (32-wave cap).
// launch_bounds stays (256,6): asking for 8 waves/EU caps the allocator at
// 32 VGPRs and spills (~100 MB/dispatch of scratch traffic, measured R1).
// Natural codegen is ~40 VGPR <= 64, so HW still reaches 8 blocks/CU.
__global__ __launch_bounds__(256, 6)
void taylor_cnn_v8_mfma(const float* __restrict__ phase, const float* __restrict__ primary,
                        const float* __restrict__ secondary, const float* __restrict__ oddeven,
                        const float* __restrict__ pA, const float* __restrict__ pBp,
                        const float* __restrict__ pT0,
                        const float* __restrict__ bng, const float* __restrict__ bnb,
                        const float* __restrict__ bnm, const float* __restrict__ bnv,
                        const float* __restrict__ w1, const float* __restrict__ b1,
                        const float* __restrict__ w2, const float* __restrict__ b2,
                        const float* __restrict__ fcw, const float* __restrict__ fcb,
                        float* __restrict__ out, int nrows)
{
    // xs: position-major, 4 ch bf16 (8 B/record). record m <-> position c0 + m - 16
    __shared__ __align__(16) unsigned int xs_i[XR * 2];   // 5.6 KB
    // y1: position-major, 8 ch bf16 (16 B/record). record q <-> position c0 + q - 8
    __shared__ __align__(16) unsigned int y1_i[XR * 4];   // 11.3 KB
    __shared__ float redA[4][16];
    __shared__ float redB[4][3];

    const int tid = threadIdx.x;
    const int row = blockIdx.x;
    const long base = (long)row * L_LEN;
    (void)nrows;

    const int lane = tid & 63;
    const int wid  = tid >> 6;
    const int n    = lane & 15;     // MFMA column (position in tile)
    const int quad = lane >> 4;     // MFMA k-block / D row-quad

    const float A  = pA[0];
    const float Bp = pBp[0];
    const float t0 = pT0[0];
    const float A_abs = fabsf(A) + 1e-8f;
    const float rAabs = 1.0f / A_abs;
    const float nBp  = -Bp;
    const float cExp = -72.134766f * rAabs;   // -50*log2(e)*rAabs: exp(-50*dn)=exp2(cExp*depth)

    float inv1, inv2, inv3, gInv0, off0, off1, off2, off3;
    {
        float iv0 = bng[0] / sqrtf(bnv[0] + 1e-5f);
        float iv1 = bng[1] / sqrtf(bnv[1] + 1e-5f);
        float iv2 = bng[2] / sqrtf(bnv[2] + 1e-5f);
        float iv3 = bng[3] / sqrtf(bnv[3] + 1e-5f);
        gInv0 = -A * iv0;                     // gate = relu(1-Bp*d^2); x0 = gate*(-A*iv0)+off0
        inv1 = iv1; inv2 = iv2; inv3 = iv3;
        off0 = bnb[0] - bnm[0] * iv0;
        off1 = bnb[1] - bnm[1] * iv1;
        off2 = bnb[2] - bnm[2] * iv2;
        off3 = bnb[3] - bnm[3] * iv3;
    }

    // ---- per-lane weight fragments ----
    bf16x8 a1;
#pragma unroll
    for (int jp = 0; jp < 8; ++jp) {
        int j = quad + 4 * (jp >> 2);
        int c = jp & 3;
        float v = (n < 8 && j < 7) ? w1[(n * 4 + c) * 7 + j] : 0.0f;
        a1[jp] = (short)f2bf(v);
    }
    bf16x8 a20, a21;
#pragma unroll
    for (int jp = 0; jp < 8; ++jp) {
        float v0 = w2[(n * 8 + jp) * 5 + quad];
        float v1 = (quad + 4 < 5) ? w2[(n * 8 + jp) * 5 + quad + 4] : 0.0f;
        a20[jp] = (short)f2bf(v0);
        a21[jp] = (short)f2bf(v1);
    }
    f32x4 cb1, cb2;   // bias seeded into MFMA C operand
#pragma unroll
    for (int r = 0; r < 4; ++r) {
        cb1[r] = b1[(quad * 4 + r) & 7];
        cb2[r] = b2[quad * 4 + r];
    }

    float s_ing = 0.0f, s_fb = 0.0f;
    float m0 = 0.f, m1 = 0.f, m2 = 0.f, m3 = 0.f;

    // trapz AUC samples early (scattered fp32 loads; overlap their latency)
    float s_auc = 0.0f;
    if (tid < 200) {
        float pos = (float)tid * (2000.0f / 199.0f);
        int i0 = (int)pos;
        if (i0 > 2000) i0 = 2000;
        int i1 = (i0 + 1 < L_LEN) ? i0 + 1 : 2000;
        float w  = pos - (float)i0;
        float d0 = fmaxf(-primary[base + i0], 0.f);
        float d1 = fmaxf(-primary[base + i1], 0.f);
        float v  = d0 * (1.0f - w) + d1 * w;
        float wt = (tid == 0 || tid == 199) ? 0.5f : 1.0f;
        s_auc = v * wt;
    }

    // ---- stage A record processor ----
    auto aRec = [&](int m, int p, bool chk) {
        bool valid = true, core = true;
        int pc = p;
        if (chk) {
            valid = ((unsigned)p < (unsigned)L_LEN);
            core  = valid && (m >= 16) && (m < 16 + CCH);
            pc = min(max(p, 0), L_LEN - 1);
        }
        float ph = phase[base + pc];
        float pf = primary[base + pc];
        float sf = secondary[base + pc];
        float oe = oddeven[base + pc];
        float dd = ph - t0;
        float g  = fmaxf(fmaf(dd * dd, nBp, 1.0f), 0.0f);
        float x0 = fmaf(g,  gInv0, off0);
        float x1 = fmaf(pf, inv1, off1);
        float x2 = fmaf(sf, inv2, off2);
        float x3 = fmaf(oe, inv3, off3);
        unsigned d0 = bfpack(x0, x1);
        unsigned d1 = bfpack(x2, x3);
        if (chk && !valid) { d0 = 0u; d1 = 0u; }
        *(uint2*)&xs_i[2 * m] = make_uint2(d0, d1);
        // soft-mask features (total==1+1e-8 -> 1.0f exactly in fp32; skip the division)
        float depth = fmaxf(-pf, 0.0f);
        float e   = fexp2(depth * cExp);                    // exp(-50*dn)
        float dip = fast_rcp(fmaf(e, 148.413159f, 1.0f));   // sigm(50(dn-0.1))
        float fb  = fast_rcp(fmaf(e, 2.35385267e17f, 1.0f));// sigm(50(dn-0.8))
        float ing = dip - fb;
        if (chk && !core) { ing = 0.f; fb = 0.f; }
        s_ing += ing;
        s_fb  += fb;
    };

    // per chunk: XR = 704 records; m = tid, tid+256, tid+512(<192)
    auto stageA = [&](int c0) {
        const int pb = c0 - 16;
        aRec(tid,       pb + tid,       true);    // m<16 straddle / core mask
        aRec(tid + 256, pb + tid + 256, false);   // interior, always valid+core
        if (tid < 192) aRec(tid + 512, pb + tid + 512, true);  // tail: core split / hi bound
    };

    // ---- stage B: conv1 via MFMA -> y1 ----
    // checks applied on tile t if (t == tLo || t >= tFrom) -- wave-uniform branch
    auto stageB = [&](int c0, int tLo, int tFrom) {
        for (int t = wid; t < NTB; t += 4) {
            int qb = 16 * t + n + quad + 5;
            FragU bu;
            bu.u2[0] = *(const uint2*)&xs_i[2 * qb];
            bu.u2[1] = *(const uint2*)&xs_i[2 * (qb + 4)];
            f32x4 d = __builtin_amdgcn_mfma_f32_16x16x32_bf16(a1, bu.v, cb1, 0, 0, 0);
            if (lane < 32) {                      // D rows 0..7 hold the 8 oc
                int q = 16 * t + n;
                unsigned w0, w1_;
                if (t == tLo || t >= tFrom) {     // wave-uniform branch
                    int p = c0 - 8 + q;
                    bool ok = ((unsigned)p < (unsigned)L_LEN);
                    w0  = ok ? bfpack(fmaxf(d[0], 0.f), fmaxf(d[1], 0.f)) : 0u;
                    w1_ = ok ? bfpack(fmaxf(d[2], 0.f), fmaxf(d[3], 0.f)) : 0u;
                } else {
                    w0  = bfpack(fmaxf(d[0], 0.f), fmaxf(d[1], 0.f));
                    w1_ = bfpack(fmaxf(d[2], 0.f), fmaxf(d[3], 0.f));
                }
                *(uint2*)&y1_i[4 * q + 2 * quad] = make_uint2(w0, w1_);
            }
        }
    };

    // ---- stage C: conv2 via MFMA, accumulate channel sums ----
    // maskT: tile whose outputs straddle position 2000 (only n==0 valid)
    auto stageC = [&](int maskT) {
        for (int t = wid; t < NTC; t += 4) {
            int q = 16 * t + n + quad + 6;
            FragU u0, u1;
            u0.u4 = *(const uint4*)&y1_i[4 * q];
            u1.u4 = *(const uint4*)&y1_i[4 * (q + 4)];
            f32x4 d = __builtin_amdgcn_mfma_f32_16x16x32_bf16(a20, u0.v, cb2, 0, 0, 0);
            d = __builtin_amdgcn_mfma_f32_16x16x32_bf16(a21, u1.v, d, 0, 0, 0);
            if (t == maskT) {                     // outputs 2000..2015: only n==0 valid
                float msk = (n == 0) ? 1.0f : 0.0f;
                m0 = fmaf(fmaxf(d[0], 0.f), msk, m0);
                m1 = fmaf(fmaxf(d[1], 0.f), msk, m1);
                m2 = fmaf(fmaxf(d[2], 0.f), msk, m2);
                m3 = fmaf(fmaxf(d[3], 0.f), msk, m3);
            } else {
                m0 += fmaxf(d[0], 0.f);
                m1 += fmaxf(d[1], 0.f);
                m2 += fmaxf(d[2], 0.f);
                m3 += fmaxf(d[3], 0.f);
            }
        }
    };

    // ---- pipeline: A0 | B0 | {A1,C0} | B1 | {A2,C1} | B2 | C2 ----
    stageA(0);
    __syncthreads();           // xs(0) ready
    stageB(0, 0, 99);          // low straddle at t=0
    __syncthreads();           // y1(0) ready; xs free
    stageA(CCH);               // xs(1) write overlaps C0's y1 reads (disjoint)
    stageC(-1);
    __syncthreads();           // xs(1) ready; y1 free
    stageB(CCH, -1, 99);       // interior chunk: no straddle
    __syncthreads();           // y1(1) ready; xs free
    stageA(2 * CCH);
    stageC(-1);
    __syncthreads();           // xs(2) ready; y1 free
    stageB(2 * CCH, -1, 41);   // hi straddle from t=41 (t=41 partial, t=42 all-invalid)
    __syncthreads();           // y1(2) ready
    stageC(41);                // outputs 2000+n at t=41: mask to n==0

    // ---- reductions ----
#pragma unroll
    for (int dlt = 8; dlt >= 1; dlt >>= 1) {
        m0 += __shfl_xor(m0, dlt);
        m1 += __shfl_xor(m1, dlt);
        m2 += __shfl_xor(m2, dlt);
        m3 += __shfl_xor(m3, dlt);
    }
    if ((lane & 15) == 0) {
        redA[wid][quad * 4 + 0] = m0;
        redA[wid][quad * 4 + 1] = m1;
        redA[wid][quad * 4 + 2] = m2;
        redA[wid][quad * 4 + 3] = m3;
    }
#pragma unroll
    for (int dlt = 32; dlt >= 1; dlt >>= 1) {
        s_ing += __shfl_xor(s_ing, dlt);
        s_fb  += __shfl_xor(s_fb,  dlt);
        s_auc += __shfl_xor(s_auc, dlt);
    }
    if (lane == 0) {
        redB[wid][0] = s_ing;
        redB[wid][1] = s_fb;
        redB[wid][2] = s_auc;
    }
    __syncthreads();

    if (tid == 0) {
        float logit = fcb[0];
#pragma unroll
        for (int oc = 0; oc < 16; ++oc) {
            float s = redA[0][oc] + redA[1][oc] + redA[2][oc] + redA[3][oc];
            logit += (s / 2001.0f) * fcw[oc];
        }
        float Sing = redB[0][0] + redB[1][0] + redB[2][0] + redB[3][0];
        float Sfb  = redB[0][1] + redB[1][1] + redB[2][1] + redB[3][1];
        float Sauc = redB[0][2] + redB[1][2] + redB[2][2] + redB[3][2];

        float auc_raw  = (float)(2.0 / 199.0) * Sauc;
        float auc_norm = auc_raw / A_abs;
        float m_ing = Sing / 2001.0f;
        float m_fb  = Sfb  / 2001.0f;
        float t14   = (Sing + Sfb) / 2001.0f + 1e-8f;
        float t12   = m_ing / t14;

        logit += Bp       * fcw[16]
               + auc_raw  * fcw[17]
               + auc_norm * fcw[18]
               + t12      * fcw[19]
               + m_fb     * fcw[20];

        out[row] = 1.0f / (1.0f + expf(-logit));
    }
}

extern "C" void kernel_launch(void* const* d_in, const int* in_sizes, int n_in,
                              void* d_out, int out_size, void* d_ws, size_t ws_size,
                              hipStream_t stream) {
    const float* phase     = (const float*)d_in[0];
    const float* primary   = (const float*)d_in[1];
    const float* secondary = (const float*)d_in[2];
    const float* oddeven   = (const float*)d_in[3];
    const float* pA        = (const float*)d_in[4];
    const float* pBp       = (const float*)d_in[5];
    const float* pT0       = (const float*)d_in[6];
    const float* bng       = (const float*)d_in[7];
    const float* bnb       = (const float*)d_in[8];
    const float* bnm       = (const float*)d_in[9];
    const float* bnv       = (const float*)d_in[10];
    const float* w1        = (const float*)d_in[11];
    const float* b1        = (const float*)d_in[12];
    const float* w2        = (const float*)d_in[13];
    const float* b2        = (const float*)d_in[14];
    const float* fcw       = (const float*)d_in[15];
    const float* fcb       = (const float*)d_in[16];
    float* out = (float*)d_out;

    int nrows = in_sizes[0] / L_LEN;   // 8192
    dim3 grid(nrows), block(256);
    hipLaunchKernelGGL(taylor_cnn_v8_mfma, grid, block, 0, stream,
                       phase, primary, secondary, oddeven, pA, pBp, pT0,
                       bng, bnb, bnm, bnv, w1, b1, w2, b2, fcw, fcb, out, nrows);
}

// Round 3
// 300.054 us; speedup vs baseline: 1.0680x; 1.0300x over previous
//
#include <hip/hip_runtime.h>
#include <math.h>

#define L_LEN 2001
#define CCH 224           // positions per chunk per wave
#define NCH 9             // chunks: 9*224 = 2016 >= 2001
#define XRECS 256         // xs records per chunk (CCH+32) -> exactly 4 per lane
#define YRECS 240         // y1 records per chunk (CCH+16)
#define NTB 15            // conv1 tiles per chunk (y1 records [0,240))
#define NTC 14            // conv2 tiles per chunk (CCH/16 outputs)

typedef __attribute__((ext_vector_type(8))) short bf16x8;
typedef __attribute__((ext_vector_type(4))) float f32x4;
#if __has_builtin(__builtin_amdgcn_cvt_pk_bf16_f32)
typedef __attribute__((ext_vector_type(2))) __bf16 bf16x2_t;
#endif

union FragU { unsigned u[4]; uint2 u2[2]; uint4 u4; bf16x8 v; };

__device__ __forceinline__ unsigned short f2bf(float f) {
    unsigned u = __builtin_bit_cast(unsigned, f);
    u += 0x7fffu + ((u >> 16) & 1u);
    return (unsigned short)(u >> 16);
}
// pack two fp32 -> bf16 pair (RNE), hi<<16 | lo
__device__ __forceinline__ unsigned bfpack(float lo, float hi) {
#if __has_builtin(__builtin_amdgcn_cvt_pk_bf16_f32)
    bf16x2_t r = __builtin_amdgcn_cvt_pk_bf16_f32(lo, hi);   // S0 -> [15:0]
    return __builtin_bit_cast(unsigned, r);
#else
    unsigned ul = __builtin_bit_cast(unsigned, lo);
    unsigned uh = __builtin_bit_cast(unsigned, hi);
    ul += 0x7fffu + ((ul >> 16) & 1u);
    uh += 0x7fffu + ((uh >> 16) & 1u);
    return __builtin_amdgcn_perm(uh, ul, 0x07060302);
#endif
}
__device__ __forceinline__ float fast_rcp(float x) { return __builtin_amdgcn_rcpf(x); }
__device__ __forceinline__ float fexp2(float x) {
#if __has_builtin(__builtin_amdgcn_exp2f)
    return __builtin_amdgcn_exp2f(x);
#else
    return __expf(x * 0.69314718f);
#endif
}

// Wave-per-row, zero barriers: each 64-lane wave owns one full row and a
// private LDS slice; stage ordering within the wave is enforced by lgkmcnt
// (compiler-inserted, in-order LDS). All 4 waves of a block work on
// independent rows -> latency bubbles decorrelate instead of ganging at
// block-wide __syncthreads (R0-R2 evidence: barrier count moved wall time,
// occupancy didn't). launch_bounds (256,4): VGPR cap 64, no spill risk
// (R1: forcing 8 waves/EU -> 32 VGPR spilled ~100 MB/dispatch).
__global__ __launch_bounds__(256, 4)
void taylor_cnn_v9_wave(const float* __restrict__ phase, const float* __restrict__ primary,
                        const float* __restrict__ secondary, const float* __restrict__ oddeven,
                        const float* __restrict__ pA, const float* __restrict__ pBp,
                        const float* __restrict__ pT0,
                        const float* __restrict__ bng, const float* __restrict__ bnb,
                        const float* __restrict__ bnm, const float* __restrict__ bnv,
                        const float* __restrict__ w1, const float* __restrict__ b1,
                        const float* __restrict__ w2, const float* __restrict__ b2,
                        const float* __restrict__ fcw, const float* __restrict__ fcb,
                        float* __restrict__ out, int nrows)
{
    // per-wave LDS slices (no cross-wave sharing, no barriers)
    __shared__ __align__(16) unsigned int xs_i[4][XRECS * 2];   // 8.0 KB
    __shared__ __align__(16) unsigned int y1_i[4][YRECS * 4];   // 15.4 KB

    const int tid = threadIdx.x;
    const int l   = tid & 63;
    const int wid = tid >> 6;
    const int row = blockIdx.x * 4 + wid;
    if (row >= nrows) return;                 // wave-uniform; legal (no barriers)
    const long base = (long)row * L_LEN;

    unsigned int* xs = xs_i[wid];
    unsigned int* y1 = y1_i[wid];

    const int n    = l & 15;     // MFMA column (position in tile)
    const int quad = l >> 4;     // MFMA k-block / D row-quad

    const float A  = pA[0];
    const float Bp = pBp[0];
    const float t0 = pT0[0];
    const float A_abs = fabsf(A) + 1e-8f;
    const float rAabs = 1.0f / A_abs;
    const float nBp  = -Bp;
    const float cExp = -72.134766f * rAabs;   // -50*log2(e)*rAabs: exp(-50*dn)=exp2(cExp*depth)

    float inv1, inv2, inv3, gInv0, off0, off1, off2, off3;
    {
        float iv0 = bng[0] / sqrtf(bnv[0] + 1e-5f);
        float iv1 = bng[1] / sqrtf(bnv[1] + 1e-5f);
        float iv2 = bng[2] / sqrtf(bnv[2] + 1e-5f);
        float iv3 = bng[3] / sqrtf(bnv[3] + 1e-5f);
        gInv0 = -A * iv0;                     // gate = relu(1-Bp*d^2); x0 = gate*(-A*iv0)+off0
        inv1 = iv1; inv2 = iv2; inv3 = iv3;
        off0 = bnb[0] - bnm[0] * iv0;
        off1 = bnb[1] - bnm[1] * iv1;
        off2 = bnb[2] - bnm[2] * iv2;
        off3 = bnb[3] - bnm[3] * iv3;
    }

    // ---- per-lane weight fragments ----
    bf16x8 a1;
#pragma unroll
    for (int jp = 0; jp < 8; ++jp) {
        int j = quad + 4 * (jp >> 2);
        int c = jp & 3;
        float v = (n < 8 && j < 7) ? w1[(n * 4 + c) * 7 + j] : 0.0f;
        a1[jp] = (short)f2bf(v);
    }
    bf16x8 a20, a21;
#pragma unroll
    for (int jp = 0; jp < 8; ++jp) {
        float v0 = w2[(n * 8 + jp) * 5 + quad];
        float v1 = (quad + 4 < 5) ? w2[(n * 8 + jp) * 5 + quad + 4] : 0.0f;
        a20[jp] = (short)f2bf(v0);
        a21[jp] = (short)f2bf(v1);
    }
    f32x4 cb1, cb2;   // bias seeded into MFMA C operand
#pragma unroll
    for (int r = 0; r < 4; ++r) {
        cb1[r] = b1[(quad * 4 + r) & 7];
        cb2[r] = b2[quad * 4 + r];
    }
    // fc weights for the CNN means (per-lane quad's 4 oc)
    float fw0 = fcw[quad * 4 + 0];
    float fw1 = fcw[quad * 4 + 1];
    float fw2 = fcw[quad * 4 + 2];
    float fw3 = fcw[quad * 4 + 3];

    float s_ing = 0.0f, s_fb = 0.0f;
    float m0 = 0.f, m1 = 0.f, m2 = 0.f, m3 = 0.f;

    // trapz AUC: 200 samples per row -> 4 per lane (last masked to l<8)
    float s_auc = 0.0f;
#pragma unroll
    for (int k = 0; k < 4; ++k) {
        int s = l + 64 * k;
        if (k < 3 || l < 8) {
            float pos = (float)s * (2000.0f / 199.0f);
            int i0 = (int)pos;
            if (i0 > 2000) i0 = 2000;
            int i1 = (i0 + 1 < L_LEN) ? i0 + 1 : 2000;
            float w  = pos - (float)i0;
            float d0 = fmaxf(-primary[base + i0], 0.f);
            float d1 = fmaxf(-primary[base + i1], 0.f);
            float v  = d0 * (1.0f - w) + d1 * w;
            float wt = (s == 0 || s == 199) ? 0.5f : 1.0f;
            s_auc += v * wt;
        }
    }

    // ---- stage A record processor (valid/core fold away for literal true) ----
    auto aRec = [&](int m, int p, bool valid, bool core) {
        float ph = phase[base + p];
        float pf = primary[base + p];
        float sf = secondary[base + p];
        float oe = oddeven[base + p];
        float dd = ph - t0;
        float g  = fmaxf(fmaf(dd * dd, nBp, 1.0f), 0.0f);
        float x0 = fmaf(g,  gInv0, off0);
        float x1 = fmaf(pf, inv1, off1);
        float x2 = fmaf(sf, inv2, off2);
        float x3 = fmaf(oe, inv3, off3);
        unsigned d0 = bfpack(x0, x1);
        unsigned d1 = bfpack(x2, x3);
        if (!valid) { d0 = 0u; d1 = 0u; }
        *(uint2*)&xs[2 * m] = make_uint2(d0, d1);
        // soft-mask features (total==1+1e-8 -> 1.0f exactly in fp32; skip division)
        float depth = fmaxf(-pf, 0.0f);
        float e   = fexp2(depth * cExp);                    // exp(-50*dn)
        float dip = fast_rcp(fmaf(e, 148.413159f, 1.0f));   // sigm(50(dn-0.1))
        float fb  = fast_rcp(fmaf(e, 2.35385267e17f, 1.0f));// sigm(50(dn-0.8))
        float ing = dip - fb;
        if (!core) { ing = 0.f; fb = 0.f; }
        s_ing += ing;
        s_fb  += fb;
    };

    // ---- per-row chunk loop: A | B | C, wave-synchronous ----
#pragma unroll 1
    for (int ch = 0; ch < NCH; ++ch) {
        const int c0 = ch * CCH;
        const int pb = c0 - 16;               // record m <-> position pb + m

        // stage A: records m = l, l+64, l+128, l+192 (positions pb+m)
        {
            // record 0 (m=l): invalid only ch==0 && l<16; core iff l>=16
            bool v0  = (ch > 0) || (l >= 16);
            bool co0 = (l >= 16);
            int  p0  = pb + l;            if (p0 < 0) p0 = 0;
            // record 3 (m=l+192): invalid only ch==8 && l>=33; core iff valid && l<48
            int  p3  = pb + l + 192;
            bool v3  = (ch < NCH - 1) || (l < 33);
            bool co3 = v3 && (l < 48);
            if (p3 > 2000) p3 = 2000;
            aRec(l,        p0,           v0,   co0);
            aRec(l + 64,   pb + l + 64,  true, true);
            aRec(l + 128,  pb + l + 128, true, true);
            aRec(l + 192,  p3,           v3,   co3);
        }

        // stage B: conv1 via MFMA -> y1 (this wave does all NTB tiles)
        const bool bLo   = (ch == 0);
        const int  bFrom = (ch == NCH - 1) ? 13 : 99;
#pragma unroll 2
        for (int t = 0; t < NTB; ++t) {
            int qb = 16 * t + n + quad + 5;
            FragU bu;
            bu.u2[0] = *(const uint2*)&xs[2 * qb];
            bu.u2[1] = *(const uint2*)&xs[2 * (qb + 4)];
            f32x4 d = __builtin_amdgcn_mfma_f32_16x16x32_bf16(a1, bu.v, cb1, 0, 0, 0);
            if (l < 32) {                     // D rows 0..7 hold the 8 oc
                int q = 16 * t + n;
                unsigned w0, w1_;
                if ((bLo && t == 0) || t >= bFrom) {   // straddle tiles
                    int p = c0 - 8 + q;
                    bool ok = ((unsigned)p < (unsigned)L_LEN);
                    w0  = ok ? bfpack(fmaxf(d[0], 0.f), fmaxf(d[1], 0.f)) : 0u;
                    w1_ = ok ? bfpack(fmaxf(d[2], 0.f), fmaxf(d[3], 0.f)) : 0u;
                } else {
                    w0  = bfpack(fmaxf(d[0], 0.f), fmaxf(d[1], 0.f));
                    w1_ = bfpack(fmaxf(d[2], 0.f), fmaxf(d[3], 0.f));
                }
                *(uint2*)&y1[4 * q + 2 * quad] = make_uint2(w0, w1_);
            }
        }

        // stage C: conv2 via MFMA, accumulate channel sums
        const int maskT = (ch == NCH - 1) ? 13 : -1;   // outputs 2000..2015: n==0 only
#pragma unroll 2
        for (int t = 0; t < NTC; ++t) {
            int q = 16 * t + n + quad + 6;
            FragU u0, u1;
            u0.u4 = *(const uint4*)&y1[4 * q];
            u1.u4 = *(const uint4*)&y1[4 * (q + 4)];
            f32x4 d = __builtin_amdgcn_mfma_f32_16x16x32_bf16(a20, u0.v, cb2, 0, 0, 0);
            d = __builtin_amdgcn_mfma_f32_16x16x32_bf16(a21, u1.v, d, 0, 0, 0);
            if (t == maskT) {
                float msk = (n == 0) ? 1.0f : 0.0f;
                m0 = fmaf(fmaxf(d[0], 0.f), msk, m0);
                m1 = fmaf(fmaxf(d[1], 0.f), msk, m1);
                m2 = fmaf(fmaxf(d[2], 0.f), msk, m2);
                m3 = fmaf(fmaxf(d[3], 0.f), msk, m3);
            } else {
                m0 += fmaxf(d[0], 0.f);
                m1 += fmaxf(d[1], 0.f);
                m2 += fmaxf(d[2], 0.f);
                m3 += fmaxf(d[3], 0.f);
            }
        }
    }

    // ---- per-wave reductions (no LDS, no barriers) ----
#pragma unroll
    for (int dlt = 8; dlt >= 1; dlt >>= 1) {     // sum over n within 16-group
        m0 += __shfl_xor(m0, dlt);
        m1 += __shfl_xor(m1, dlt);
        m2 += __shfl_xor(m2, dlt);
        m3 += __shfl_xor(m3, dlt);
    }
    // dot with fc weights; each 16-group contributes its quad's 4 oc once
    float part = m0 * fw0 + m1 * fw1 + m2 * fw2 + m3 * fw3;
    part = (n == 0) ? part : 0.0f;
    part += __shfl_xor(part, 16);
    part += __shfl_xor(part, 32);
#pragma unroll
    for (int dlt = 32; dlt >= 1; dlt >>= 1) {
        s_ing += __shfl_xor(s_ing, dlt);
        s_fb  += __shfl_xor(s_fb,  dlt);
        s_auc += __shfl_xor(s_auc, dlt);
    }

    if (l == 0) {
        float logit = fcb[0] + part * (1.0f / 2001.0f);
        float auc_raw  = (float)(2.0 / 199.0) * s_auc;
        float auc_norm = auc_raw / A_abs;
        float m_ing = s_ing / 2001.0f;
        float m_fb  = s_fb  / 2001.0f;
        float t14   = (s_ing + s_fb) / 2001.0f + 1e-8f;
        float t12   = m_ing / t14;

        logit += Bp       * fcw[16]
               + auc_raw  * fcw[17]
               + auc_norm * fcw[18]
               + t12      * fcw[19]
               + m_fb     * fcw[20];

        out[row] = 1.0f / (1.0f + expf(-logit));
    }
}

extern "C" void kernel_launch(void* const* d_in, const int* in_sizes, int n_in,
                              void* d_out, int out_size, void* d_ws, size_t ws_size,
                              hipStream_t stream) {
    const float* phase     = (const float*)d_in[0];
    const float* primary   = (const float*)d_in[1];
    const float* secondary = (const float*)d_in[2];
    const float* oddeven   = (const float*)d_in[3];
    const float* pA        = (const float*)d_in[4];
    const float* pBp       = (const float*)d_in[5];
    const float* pT0       = (const float*)d_in[6];
    const float* bng       = (const float*)d_in[7];
    const float* bnb       = (const float*)d_in[8];
    const float* bnm       = (const float*)d_in[9];
    const float* bnv       = (const float*)d_in[10];
    const float* w1        = (const float*)d_in[11];
    const float* b1        = (const float*)d_in[12];
    const float* w2        = (const float*)d_in[13];
    const float* b2        = (const float*)d_in[14];
    const float* fcw       = (const float*)d_in[15];
    const float* fcb       = (const float*)d_in[16];
    float* out = (float*)d_out;

    int nrows = in_sizes[0] / L_LEN;   // 8192
    dim3 grid((nrows + 3) / 4), block(256);
    hipLaunchKernelGGL(taylor_cnn_v9_wave, grid, block, 0, stream,
                       phase, primary, secondary, oddeven, pA, pBp, pT0,
                       bng, bnb, bnm, bnv, w1, b1, w2, b2, fcw, fcb, out, nrows);
}

// Round 4
// 291.163 us; speedup vs baseline: 1.1006x; 1.0305x over previous
//
#include <hip/hip_runtime.h>
#include <math.h>

#define L_LEN 2001
#define CCH 224           // positions per chunk per wave
#define NCH 9             // chunks: 9*224 = 2016 >= 2001
#define XRECS 256         // xs records per chunk (CCH+32) -> exactly 4 per lane
#define YRECS 240         // y1 records per chunk (CCH+16)
#define NTC 14            // conv2 tiles per chunk (CCH/16 outputs)

typedef __attribute__((ext_vector_type(8))) short bf16x8;
typedef __attribute__((ext_vector_type(4))) float f32x4;
typedef __attribute__((ext_vector_type(16))) float f32x16;
typedef __attribute__((ext_vector_type(4), aligned(4))) float f32x4u;  // unaligned-tolerant
#if __has_builtin(__builtin_amdgcn_cvt_pk_bf16_f32)
typedef __attribute__((ext_vector_type(2))) __bf16 bf16x2_t;
#endif

union FragU { unsigned u[4]; uint2 u2[2]; uint4 u4; bf16x8 v; };

__device__ __forceinline__ unsigned short f2bf(float f) {
    unsigned u = __builtin_bit_cast(unsigned, f);
    u += 0x7fffu + ((u >> 16) & 1u);
    return (unsigned short)(u >> 16);
}
// pack two fp32 -> bf16 pair (RNE), hi<<16 | lo
__device__ __forceinline__ unsigned bfpack(float lo, float hi) {
#if __has_builtin(__builtin_amdgcn_cvt_pk_bf16_f32)
    bf16x2_t r = __builtin_amdgcn_cvt_pk_bf16_f32(lo, hi);   // S0 -> [15:0]
    return __builtin_bit_cast(unsigned, r);
#else
    unsigned ul = __builtin_bit_cast(unsigned, lo);
    unsigned uh = __builtin_bit_cast(unsigned, hi);
    ul += 0x7fffu + ((ul >> 16) & 1u);
    uh += 0x7fffu + ((uh >> 16) & 1u);
    return __builtin_amdgcn_perm(uh, ul, 0x07060302);
#endif
}
__device__ __forceinline__ float fast_rcp(float x) { return __builtin_amdgcn_rcpf(x); }
__device__ __forceinline__ float fexp2(float x) {
#if __has_builtin(__builtin_amdgcn_exp2f)
    return __builtin_amdgcn_exp2f(x);
#else
    return __expf(x * 0.69314718f);
#endif
}

// Wave-per-row, zero barriers (R3). R4: kernel is VALU-issue-bound
// (measured VALUBusy*wall == static issue count): conv1 moved to
// 32x32x16 MFMA (all-lane pack, half the per-position overhead) and
// stage A vectorized to 4 consecutive positions/lane (float4 loads,
// b128 LDS writes). y1/xs layouts unchanged -> conv2 path untouched.
__global__ __launch_bounds__(256, 4)
void taylor_cnn_v10_wave(const float* __restrict__ phase, const float* __restrict__ primary,
                         const float* __restrict__ secondary, const float* __restrict__ oddeven,
                         const float* __restrict__ pA, const float* __restrict__ pBp,
                         const float* __restrict__ pT0,
                         const float* __restrict__ bng, const float* __restrict__ bnb,
                         const float* __restrict__ bnm, const float* __restrict__ bnv,
                         const float* __restrict__ w1, const float* __restrict__ b1,
                         const float* __restrict__ w2, const float* __restrict__ b2,
                         const float* __restrict__ fcw, const float* __restrict__ fcb,
                         float* __restrict__ out, int nrows)
{
    // per-wave LDS slices (no cross-wave sharing, no barriers)
    __shared__ __align__(16) unsigned int xs_i[4][XRECS * 2];   // 8.0 KB
    __shared__ __align__(16) unsigned int y1_i[4][YRECS * 4];   // 15.4 KB

    const int tid = threadIdx.x;
    const int l   = tid & 63;
    const int wid = tid >> 6;
    const int row = blockIdx.x * 4 + wid;
    if (row >= nrows) return;                 // wave-uniform; legal (no barriers)
    const long base = (long)row * L_LEN;

    unsigned int* xs = xs_i[wid];
    unsigned int* y1 = y1_i[wid];

    const int n    = l & 15;     // 16x16 MFMA column (conv2 / tail tile)
    const int quad = l >> 4;     // 16x16 MFMA k-block / D row-quad
    const int c    = l & 31;     // 32x32 MFMA column (conv1)
    const int h    = l >> 5;     // 32x32 MFMA half

    const float A  = pA[0];
    const float Bp = pBp[0];
    const float t0 = pT0[0];
    const float A_abs = fabsf(A) + 1e-8f;
    const float rAabs = 1.0f / A_abs;
    const float nBp  = -Bp;
    const float cExp = -72.134766f * rAabs;   // -50*log2(e)*rAabs: exp(-50*dn)=exp2(cExp*depth)

    float inv1, inv2, inv3, gInv0, off0, off1, off2, off3;
    {
        float iv0 = bng[0] / sqrtf(bnv[0] + 1e-5f);
        float iv1 = bng[1] / sqrtf(bnv[1] + 1e-5f);
        float iv2 = bng[2] / sqrtf(bnv[2] + 1e-5f);
        float iv3 = bng[3] / sqrtf(bnv[3] + 1e-5f);
        gInv0 = -A * iv0;                     // gate = relu(1-Bp*d^2); x0 = gate*(-A*iv0)+off0
        inv1 = iv1; inv2 = iv2; inv3 = iv3;
        off0 = bnb[0] - bnm[0] * iv0;
        off1 = bnb[1] - bnm[1] * iv1;
        off2 = bnb[2] - bnm[2] * iv2;
        off3 = bnb[3] - bnm[3] * iv3;
    }

    // ---- conv1 32x32x16 A-fragments: row = l&31 (oc), k = 8*h + j ----
    //   MFMA0: (ch = j&3, tap = (j>>2) + 2h)       taps 0..3
    //   MFMA1: (ch = j&3, tap = 4 + (j>>2) + 2h)   taps 4..6 (tap7 -> 0)
    bf16x8 a32_0, a32_1;
#pragma unroll
    for (int jp = 0; jp < 8; ++jp) {
        int ch_  = jp & 3;
        int tap0 = (jp >> 2) + 2 * h;
        int tap1 = 4 + (jp >> 2) + 2 * h;
        float v0 = (c < 8) ? w1[(c * 4 + ch_) * 7 + tap0] : 0.0f;
        float v1 = (c < 8 && tap1 < 7) ? w1[(c * 4 + ch_) * 7 + tap1] : 0.0f;
        a32_0[jp] = (short)f2bf(v0);
        a32_1[jp] = (short)f2bf(v1);
    }
    // conv1 bias in C operand: D reg r<4 -> row (r&3)+4h
    f32x16 cb32;
#pragma unroll
    for (int r = 0; r < 16; ++r)
        cb32[r] = (r < 4) ? b1[(r & 3) + 4 * h] : 0.0f;

    // ---- old 16x16x32 conv1 fragment (tail tile, records 224..239) ----
    bf16x8 a1;
#pragma unroll
    for (int jp = 0; jp < 8; ++jp) {
        int j = quad + 4 * (jp >> 2);
        int cc = jp & 3;
        float v = (n < 8 && j < 7) ? w1[(n * 4 + cc) * 7 + j] : 0.0f;
        a1[jp] = (short)f2bf(v);
    }
    // ---- conv2 fragments (unchanged) ----
    bf16x8 a20, a21;
#pragma unroll
    for (int jp = 0; jp < 8; ++jp) {
        float v0 = w2[(n * 8 + jp) * 5 + quad];
        float v1 = (quad + 4 < 5) ? w2[(n * 8 + jp) * 5 + quad + 4] : 0.0f;
        a20[jp] = (short)f2bf(v0);
        a21[jp] = (short)f2bf(v1);
    }
    f32x4 cb1, cb2;
#pragma unroll
    for (int r = 0; r < 4; ++r) {
        cb1[r] = b1[(quad * 4 + r) & 7];
        cb2[r] = b2[quad * 4 + r];
    }
    // fc weights for the CNN means (per-lane quad's 4 oc)
    float fw0 = fcw[quad * 4 + 0];
    float fw1 = fcw[quad * 4 + 1];
    float fw2 = fcw[quad * 4 + 2];
    float fw3 = fcw[quad * 4 + 3];

    float s_ing = 0.0f, s_fb = 0.0f;
    float m0 = 0.f, m1 = 0.f, m2 = 0.f, m3 = 0.f;

    // trapz AUC: 200 samples per row -> 4 per lane (last masked to l<8)
    float s_auc = 0.0f;
#pragma unroll
    for (int k = 0; k < 4; ++k) {
        int s = l + 64 * k;
        if (k < 3 || l < 8) {
            float pos = (float)s * (2000.0f / 199.0f);
            int i0 = (int)pos;
            if (i0 > 2000) i0 = 2000;
            int i1 = (i0 + 1 < L_LEN) ? i0 + 1 : 2000;
            float w  = pos - (float)i0;
            float d0 = fmaxf(-primary[base + i0], 0.f);
            float d1 = fmaxf(-primary[base + i1], 0.f);
            float v  = d0 * (1.0f - w) + d1 * w;
            float wt = (s == 0 || s == 199) ? 0.5f : 1.0f;
            s_auc += v * wt;
        }
    }

    // ---- stage A scalar record processor (last chunk only) ----
    auto aRec = [&](int m, int p, bool valid, bool core) {
        float ph = phase[base + p];
        float pf = primary[base + p];
        float sf = secondary[base + p];
        float oe = oddeven[base + p];
        float dd = ph - t0;
        float g  = fmaxf(fmaf(dd * dd, nBp, 1.0f), 0.0f);
        float x0 = fmaf(g,  gInv0, off0);
        float x1 = fmaf(pf, inv1, off1);
        float x2 = fmaf(sf, inv2, off2);
        float x3 = fmaf(oe, inv3, off3);
        unsigned d0 = bfpack(x0, x1);
        unsigned d1 = bfpack(x2, x3);
        if (!valid) { d0 = 0u; d1 = 0u; }
        *(uint2*)&xs[2 * m] = make_uint2(d0, d1);
        float depth = fmaxf(-pf, 0.0f);
        float e   = fexp2(depth * cExp);
        float dip = fast_rcp(fmaf(e, 148.413159f, 1.0f));
        float fb  = fast_rcp(fmaf(e, 2.35385267e17f, 1.0f));
        float ing = dip - fb;
        if (!core) { ing = 0.f; fb = 0.f; }
        s_ing += ing;
        s_fb  += fb;
    };

    const float coreMask = (l >= 4 && l < 60) ? 1.0f : 0.0f;   // records 16..239

    // ---- per-row chunk loop: A | B | C, wave-synchronous ----
#pragma unroll 1
    for (int ch = 0; ch < NCH; ++ch) {
        const int c0 = ch * CCH;
        const int pb = c0 - 16;               // record m <-> position pb + m
        const bool isFirst = (ch == 0);
        const bool isLast  = (ch == NCH - 1);

        // ======== stage A ========
        if (!isLast) {
            // fast path: lane l owns records 4l..4l+3 (consecutive positions)
            int p0 = pb + 4 * l;
            bool zl = false;
            if (isFirst && p0 < 0) { p0 = 0; zl = true; }   // ch0 lanes 0..3
            const f32x4u ph4 = *(const f32x4u*)&phase[base + p0];
            const f32x4u pf4 = *(const f32x4u*)&primary[base + p0];
            const f32x4u sf4 = *(const f32x4u*)&secondary[base + p0];
            const f32x4u oe4 = *(const f32x4u*)&oddeven[base + p0];
            unsigned dw[8];
            float ingA = 0.f, fbA = 0.f;
#pragma unroll
            for (int j = 0; j < 4; ++j) {
                float dd = ph4[j] - t0;
                float g  = fmaxf(fmaf(dd * dd, nBp, 1.0f), 0.0f);
                float x0 = fmaf(g,      gInv0, off0);
                float x1 = fmaf(pf4[j], inv1,  off1);
                float x2 = fmaf(sf4[j], inv2,  off2);
                float x3 = fmaf(oe4[j], inv3,  off3);
                dw[2 * j]     = bfpack(x0, x1);
                dw[2 * j + 1] = bfpack(x2, x3);
                float depth = fmaxf(-pf4[j], 0.0f);
                float e   = fexp2(depth * cExp);
                float dip = fast_rcp(fmaf(e, 148.413159f, 1.0f));
                float fb  = fast_rcp(fmaf(e, 2.35385267e17f, 1.0f));
                ingA += dip - fb;
                fbA  += fb;
            }
            if (zl) {
#pragma unroll
                for (int j = 0; j < 8; ++j) dw[j] = 0u;
            }
            *(uint4*)&xs[8 * l]     = make_uint4(dw[0], dw[1], dw[2], dw[3]);
            *(uint4*)&xs[8 * l + 4] = make_uint4(dw[4], dw[5], dw[6], dw[7]);
            s_ing = fmaf(ingA, coreMask, s_ing);
            s_fb  = fmaf(fbA,  coreMask, s_fb);
        } else {
            // last chunk: scalar path with per-record valid/core
            bool v0  = (l >= 16);             // ch>0 so halo-low is valid data,
            bool co0 = (l >= 16);             // but core only from m>=16
            int  p0s = pb + l;
            int  p3  = pb + l + 192;
            bool v3  = (l < 33);              // p<=2000
            bool co3 = v3 && (l < 48);
            if (p3 > 2000) p3 = 2000;
            aRec(l,        p0s,          true, co0); (void)v0;
            aRec(l + 64,   pb + l + 64,  true, true);
            aRec(l + 128,  pb + l + 128, true, true);
            aRec(l + 192,  p3,           v3,   co3);
        }

        // ======== stage B: conv1 ========
        // 7x 32-wide tiles (records 0..223) via 32x32x16, then 16-wide tail
        {
            const int cb = c + 2 * h + 5;     // xs record base offset for this lane
#pragma unroll 2
            for (int T = 0; T < 7; ++T) {
                const int R0 = 32 * T + cb;
                FragU b0, b1f;
                b0.u2[0]  = *(const uint2*)&xs[2 * R0];
                b0.u2[1]  = *(const uint2*)&xs[2 * R0 + 2];
                b1f.u2[0] = *(const uint2*)&xs[2 * R0 + 8];
                b1f.u2[1] = *(const uint2*)&xs[2 * R0 + 10];
                f32x16 d = __builtin_amdgcn_mfma_f32_32x32x16_bf16(a32_0, b0.v,  cb32, 0, 0, 0);
                d        = __builtin_amdgcn_mfma_f32_32x32x16_bf16(a32_1, b1f.v, d,    0, 0, 0);
                unsigned w0  = bfpack(fmaxf(d[0], 0.f), fmaxf(d[1], 0.f));
                unsigned w1_ = bfpack(fmaxf(d[2], 0.f), fmaxf(d[3], 0.f));
                if (isFirst && T == 0) {          // pos = c-8 < 0
                    if (c < 8) { w0 = 0u; w1_ = 0u; }
                }
                if (isLast && T == 6) {           // pos = 1976+c > 2000
                    if (c > 24) { w0 = 0u; w1_ = 0u; }
                }
                *(uint2*)&y1[4 * (32 * T + c) + 2 * h] = make_uint2(w0, w1_);
            }
            // tail: y1 records 224..239
            if (!isLast) {
                int qb = 224 + n + quad + 5;
                FragU bu;
                bu.u2[0] = *(const uint2*)&xs[2 * qb];
                bu.u2[1] = *(const uint2*)&xs[2 * (qb + 4)];
                f32x4 d = __builtin_amdgcn_mfma_f32_16x16x32_bf16(a1, bu.v, cb1, 0, 0, 0);
                if (l < 32) {
                    unsigned w0  = bfpack(fmaxf(d[0], 0.f), fmaxf(d[1], 0.f));
                    unsigned w1_ = bfpack(fmaxf(d[2], 0.f), fmaxf(d[3], 0.f));
                    *(uint2*)&y1[4 * (224 + n) + 2 * quad] = make_uint2(w0, w1_);
                }
            } else {
                // positions 2008..2023: all beyond the row -> zero records
                if (l < 32)
                    *(uint2*)&y1[4 * (224 + n) + 2 * quad] = make_uint2(0u, 0u);
            }
        }

        // ======== stage C: conv2, accumulate channel sums ========
        const int maskT = isLast ? 13 : -1;   // outputs 2000..2015: n==0 only
#pragma unroll 2
        for (int t = 0; t < NTC; ++t) {
            int q = 16 * t + n + quad + 6;
            FragU u0, u1;
            u0.u4 = *(const uint4*)&y1[4 * q];
            u1.u4 = *(const uint4*)&y1[4 * (q + 4)];
            f32x4 d = __builtin_amdgcn_mfma_f32_16x16x32_bf16(a20, u0.v, cb2, 0, 0, 0);
            d = __builtin_amdgcn_mfma_f32_16x16x32_bf16(a21, u1.v, d, 0, 0, 0);
            if (t == maskT) {
                float msk = (n == 0) ? 1.0f : 0.0f;
                m0 = fmaf(fmaxf(d[0], 0.f), msk, m0);
                m1 = fmaf(fmaxf(d[1], 0.f), msk, m1);
                m2 = fmaf(fmaxf(d[2], 0.f), msk, m2);
                m3 = fmaf(fmaxf(d[3], 0.f), msk, m3);
            } else {
                m0 += fmaxf(d[0], 0.f);
                m1 += fmaxf(d[1], 0.f);
                m2 += fmaxf(d[2], 0.f);
                m3 += fmaxf(d[3], 0.f);
            }
        }
    }

    // ---- per-wave reductions (no LDS, no barriers) ----
#pragma unroll
    for (int dlt = 8; dlt >= 1; dlt >>= 1) {     // sum over n within 16-group
        m0 += __shfl_xor(m0, dlt);
        m1 += __shfl_xor(m1, dlt);
        m2 += __shfl_xor(m2, dlt);
        m3 += __shfl_xor(m3, dlt);
    }
    float part = m0 * fw0 + m1 * fw1 + m2 * fw2 + m3 * fw3;
    part = (n == 0) ? part : 0.0f;
    part += __shfl_xor(part, 16);
    part += __shfl_xor(part, 32);
#pragma unroll
    for (int dlt = 32; dlt >= 1; dlt >>= 1) {
        s_ing += __shfl_xor(s_ing, dlt);
        s_fb  += __shfl_xor(s_fb,  dlt);
        s_auc += __shfl_xor(s_auc, dlt);
    }

    if (l == 0) {
        float logit = fcb[0] + part * (1.0f / 2001.0f);
        float auc_raw  = (float)(2.0 / 199.0) * s_auc;
        float auc_norm = auc_raw / A_abs;
        float m_ing = s_ing / 2001.0f;
        float m_fb  = s_fb  / 2001.0f;
        float t14   = (s_ing + s_fb) / 2001.0f + 1e-8f;
        float t12   = m_ing / t14;

        logit += Bp       * fcw[16]
               + auc_raw  * fcw[17]
               + auc_norm * fcw[18]
               + t12      * fcw[19]
               + m_fb     * fcw[20];

        out[row] = 1.0f / (1.0f + expf(-logit));
    }
}

extern "C" void kernel_launch(void* const* d_in, const int* in_sizes, int n_in,
                              void* d_out, int out_size, void* d_ws, size_t ws_size,
                              hipStream_t stream) {
    const float* phase     = (const float*)d_in[0];
    const float* primary   = (const float*)d_in[1];
    const float* secondary = (const float*)d_in[2];
    const float* oddeven   = (const float*)d_in[3];
    const float* pA        = (const float*)d_in[4];
    const float* pBp       = (const float*)d_in[5];
    const float* pT0       = (const float*)d_in[6];
    const float* bng       = (const float*)d_in[7];
    const float* bnb       = (const float*)d_in[8];
    const float* bnm       = (const float*)d_in[9];
    const float* bnv       = (const float*)d_in[10];
    const float* w1        = (const float*)d_in[11];
    const float* b1        = (const float*)d_in[12];
    const float* w2        = (const float*)d_in[13];
    const float* b2        = (const float*)d_in[14];
    const float* fcw       = (const float*)d_in[15];
    const float* fcb       = (const float*)d_in[16];
    float* out = (float*)d_out;

    int nrows = in_sizes[0] / L_LEN;   // 8192
    dim3 grid((nrows + 3) / 4), block(256);
    hipLaunchKernelGGL(taylor_cnn_v10_wave, grid, block, 0, stream,
                       phase, primary, secondary, oddeven, pA, pBp, pT0,
                       bng, bnb, bnm, bnv, w1, b1, w2, b2, fcw, fcb, out, nrows);
}

// Round 5
// 281.885 us; speedup vs baseline: 1.1368x; 1.0329x over previous
//
#include <hip/hip_runtime.h>
#include <math.h>

#define L_LEN 2001
#define CCH 224           // positions per chunk per wave
#define NCH 9             // chunks: 9*224 = 2016 >= 2001
#define XRECS 256         // xs records per chunk (CCH+32) -> exactly 4 per lane
#define YRECS 240         // y1 records per chunk (CCH+16)
#define NTC 14            // conv2 tiles per chunk (CCH/16 outputs)

typedef __attribute__((ext_vector_type(8))) short bf16x8;
typedef __attribute__((ext_vector_type(4))) float f32x4;
typedef __attribute__((ext_vector_type(16))) float f32x16;
typedef __attribute__((ext_vector_type(4), aligned(4))) float f32x4u;  // unaligned-tolerant
#if __has_builtin(__builtin_amdgcn_cvt_pk_bf16_f32)
typedef __attribute__((ext_vector_type(2))) __bf16 bf16x2_t;
#endif

union FragU { unsigned u[4]; uint2 u2[2]; uint4 u4; bf16x8 v; };

__device__ __forceinline__ unsigned short f2bf(float f) {
    unsigned u = __builtin_bit_cast(unsigned, f);
    u += 0x7fffu + ((u >> 16) & 1u);
    return (unsigned short)(u >> 16);
}
// pack two fp32 -> bf16 pair (RNE), hi<<16 | lo
__device__ __forceinline__ unsigned bfpack(float lo, float hi) {
#if __has_builtin(__builtin_amdgcn_cvt_pk_bf16_f32)
    bf16x2_t r = __builtin_amdgcn_cvt_pk_bf16_f32(lo, hi);   // S0 -> [15:0]
    return __builtin_bit_cast(unsigned, r);
#else
    unsigned ul = __builtin_bit_cast(unsigned, lo);
    unsigned uh = __builtin_bit_cast(unsigned, hi);
    ul += 0x7fffu + ((ul >> 16) & 1u);
    uh += 0x7fffu + ((uh >> 16) & 1u);
    return __builtin_amdgcn_perm(uh, ul, 0x07060302);
#endif
}
__device__ __forceinline__ float fast_rcp(float x) { return __builtin_amdgcn_rcpf(x); }
__device__ __forceinline__ float fexp2(float x) {
#if __has_builtin(__builtin_amdgcn_exp2f)
    return __builtin_amdgcn_exp2f(x);
#else
    return __expf(x * 0.69314718f);
#endif
}

// Wave-per-row, zero barriers (R3); 32x32 conv1 + vectorized stage A (R4).
// R5: T14 register prefetch -- next chunk's 16 floats/lane are loaded at the
// top of each iteration and consumed the NEXT iteration, so VMEM latency
// hides under the current chunk's B+C (MFMA+LDS) phase. +16 VGPR.
__global__ __launch_bounds__(256, 4)
void taylor_cnn_v11_wave(const float* __restrict__ phase, const float* __restrict__ primary,
                         const float* __restrict__ secondary, const float* __restrict__ oddeven,
                         const float* __restrict__ pA, const float* __restrict__ pBp,
                         const float* __restrict__ pT0,
                         const float* __restrict__ bng, const float* __restrict__ bnb,
                         const float* __restrict__ bnm, const float* __restrict__ bnv,
                         const float* __restrict__ w1, const float* __restrict__ b1,
                         const float* __restrict__ w2, const float* __restrict__ b2,
                         const float* __restrict__ fcw, const float* __restrict__ fcb,
                         float* __restrict__ out, int nrows)
{
    // per-wave LDS slices (no cross-wave sharing, no barriers)
    __shared__ __align__(16) unsigned int xs_i[4][XRECS * 2];   // 8.0 KB
    __shared__ __align__(16) unsigned int y1_i[4][YRECS * 4];   // 15.4 KB

    const int tid = threadIdx.x;
    const int l   = tid & 63;
    const int wid = tid >> 6;
    const int row = blockIdx.x * 4 + wid;
    if (row >= nrows) return;                 // wave-uniform; legal (no barriers)
    const long base = (long)row * L_LEN;

    unsigned int* xs = xs_i[wid];
    unsigned int* y1 = y1_i[wid];

    const int n    = l & 15;     // 16x16 MFMA column (conv2 / tail tile)
    const int quad = l >> 4;     // 16x16 MFMA k-block / D row-quad
    const int c    = l & 31;     // 32x32 MFMA column (conv1)
    const int h    = l >> 5;     // 32x32 MFMA half

    const float A  = pA[0];
    const float Bp = pBp[0];
    const float t0 = pT0[0];
    const float A_abs = fabsf(A) + 1e-8f;
    const float rAabs = 1.0f / A_abs;
    const float nBp  = -Bp;
    const float cExp = -72.134766f * rAabs;   // -50*log2(e)*rAabs: exp(-50*dn)=exp2(cExp*depth)

    float inv1, inv2, inv3, gInv0, off0, off1, off2, off3;
    {
        float iv0 = bng[0] / sqrtf(bnv[0] + 1e-5f);
        float iv1 = bng[1] / sqrtf(bnv[1] + 1e-5f);
        float iv2 = bng[2] / sqrtf(bnv[2] + 1e-5f);
        float iv3 = bng[3] / sqrtf(bnv[3] + 1e-5f);
        gInv0 = -A * iv0;                     // gate = relu(1-Bp*d^2); x0 = gate*(-A*iv0)+off0
        inv1 = iv1; inv2 = iv2; inv3 = iv3;
        off0 = bnb[0] - bnm[0] * iv0;
        off1 = bnb[1] - bnm[1] * iv1;
        off2 = bnb[2] - bnm[2] * iv2;
        off3 = bnb[3] - bnm[3] * iv3;
    }

    // ---- conv1 32x32x16 A-fragments: row = l&31 (oc), k = 8*h + j ----
    //   MFMA0: (ch = j&3, tap = (j>>2) + 2h)       taps 0..3
    //   MFMA1: (ch = j&3, tap = 4 + (j>>2) + 2h)   taps 4..6 (tap7 -> 0)
    bf16x8 a32_0, a32_1;
#pragma unroll
    for (int jp = 0; jp < 8; ++jp) {
        int ch_  = jp & 3;
        int tap0 = (jp >> 2) + 2 * h;
        int tap1 = 4 + (jp >> 2) + 2 * h;
        float v0 = (c < 8) ? w1[(c * 4 + ch_) * 7 + tap0] : 0.0f;
        float v1 = (c < 8 && tap1 < 7) ? w1[(c * 4 + ch_) * 7 + tap1] : 0.0f;
        a32_0[jp] = (short)f2bf(v0);
        a32_1[jp] = (short)f2bf(v1);
    }
    // conv1 bias in C operand: D reg r<4 -> row (r&3)+4h
    f32x16 cb32;
#pragma unroll
    for (int r = 0; r < 16; ++r)
        cb32[r] = (r < 4) ? b1[(r & 3) + 4 * h] : 0.0f;

    // ---- old 16x16x32 conv1 fragment (tail tile, records 224..239) ----
    bf16x8 a1;
#pragma unroll
    for (int jp = 0; jp < 8; ++jp) {
        int j = quad + 4 * (jp >> 2);
        int cc = jp & 3;
        float v = (n < 8 && j < 7) ? w1[(n * 4 + cc) * 7 + j] : 0.0f;
        a1[jp] = (short)f2bf(v);
    }
    // ---- conv2 fragments (unchanged) ----
    bf16x8 a20, a21;
#pragma unroll
    for (int jp = 0; jp < 8; ++jp) {
        float v0 = w2[(n * 8 + jp) * 5 + quad];
        float v1 = (quad + 4 < 5) ? w2[(n * 8 + jp) * 5 + quad + 4] : 0.0f;
        a20[jp] = (short)f2bf(v0);
        a21[jp] = (short)f2bf(v1);
    }
    f32x4 cb1, cb2;
#pragma unroll
    for (int r = 0; r < 4; ++r) {
        cb1[r] = b1[(quad * 4 + r) & 7];
        cb2[r] = b2[quad * 4 + r];
    }
    // fc weights for the CNN means (per-lane quad's 4 oc)
    float fw0 = fcw[quad * 4 + 0];
    float fw1 = fcw[quad * 4 + 1];
    float fw2 = fcw[quad * 4 + 2];
    float fw3 = fcw[quad * 4 + 3];

    float s_dip = 0.0f, s_fb = 0.0f;          // sum(dip), sum(fb); ing = dip-fb folded out
    float m0 = 0.f, m1 = 0.f, m2 = 0.f, m3 = 0.f;

    // trapz AUC: 200 samples per row -> 4 per lane (last masked to l<8)
    float s_auc = 0.0f;
#pragma unroll
    for (int k = 0; k < 4; ++k) {
        int s = l + 64 * k;
        if (k < 3 || l < 8) {
            float pos = (float)s * (2000.0f / 199.0f);
            int i0 = (int)pos;
            if (i0 > 2000) i0 = 2000;
            int i1 = (i0 + 1 < L_LEN) ? i0 + 1 : 2000;
            float w  = pos - (float)i0;
            float d0 = fmaxf(-primary[base + i0], 0.f);
            float d1 = fmaxf(-primary[base + i1], 0.f);
            float v  = d0 * (1.0f - w) + d1 * w;
            float wt = (s == 0 || s == 199) ? 0.5f : 1.0f;
            s_auc += v * wt;
        }
    }

    // ---- stage A scalar record processor (last chunk only) ----
    auto aRec = [&](int m, int p, bool valid, bool core) {
        float ph = phase[base + p];
        float pf = primary[base + p];
        float sf = secondary[base + p];
        float oe = oddeven[base + p];
        float dd = ph - t0;
        float g  = fmaxf(fmaf(dd * dd, nBp, 1.0f), 0.0f);
        float x0 = fmaf(g,  gInv0, off0);
        float x1 = fmaf(pf, inv1, off1);
        float x2 = fmaf(sf, inv2, off2);
        float x3 = fmaf(oe, inv3, off3);
        unsigned d0 = bfpack(x0, x1);
        unsigned d1 = bfpack(x2, x3);
        if (!valid) { d0 = 0u; d1 = 0u; }
        *(uint2*)&xs[2 * m] = make_uint2(d0, d1);
        float depth = fmaxf(-pf, 0.0f);
        float e   = fexp2(depth * cExp);
        float dip = fast_rcp(fmaf(e, 148.413159f, 1.0f));
        float fb  = fast_rcp(fmaf(e, 2.35385267e17f, 1.0f));
        if (!core) { dip = 0.f; fb = 0.f; }
        s_dip += dip;
        s_fb  += fb;
    };

    const float coreMask = (l >= 4 && l < 60) ? 1.0f : 0.0f;   // records 16..239

    // ---- T14 prefetch: preload chunk 0 ----
    f32x4u ph4, pf4, sf4, oe4;
    {
        int p0 = 4 * l - 16; if (p0 < 0) p0 = 0;
        ph4 = *(const f32x4u*)&phase[base + p0];
        pf4 = *(const f32x4u*)&primary[base + p0];
        sf4 = *(const f32x4u*)&secondary[base + p0];
        oe4 = *(const f32x4u*)&oddeven[base + p0];
    }

    // ---- vector chunks 0..7: A | B | C, wave-synchronous ----
#pragma unroll 1
    for (int ch = 0; ch < NCH - 1; ++ch) {
        const int c0 = ch * CCH;
        const bool isFirst = (ch == 0);

        // issue NEXT chunk's loads now; waitcnt lands at next iteration's
        // stage A, i.e. latency hides under this chunk's B+C
        f32x4u nph, npf, nsf, noe;
        if (ch < NCH - 2) {
            const long pn = base + (c0 + CCH - 16 + 4 * l);
            nph = *(const f32x4u*)&phase[pn];
            npf = *(const f32x4u*)&primary[pn];
            nsf = *(const f32x4u*)&secondary[pn];
            noe = *(const f32x4u*)&oddeven[pn];
        } else {
            nph = ph4; npf = pf4; nsf = sf4; noe = oe4;   // dead
        }

        // ======== stage A (from prefetched regs) ========
        {
            unsigned dw[8];
            float dipA = 0.f, fbA = 0.f;
#pragma unroll
            for (int j = 0; j < 4; ++j) {
                float dd = ph4[j] - t0;
                float g  = fmaxf(fmaf(dd * dd, nBp, 1.0f), 0.0f);
                float x0 = fmaf(g,      gInv0, off0);
                float x1 = fmaf(pf4[j], inv1,  off1);
                float x2 = fmaf(sf4[j], inv2,  off2);
                float x3 = fmaf(oe4[j], inv3,  off3);
                dw[2 * j]     = bfpack(x0, x1);
                dw[2 * j + 1] = bfpack(x2, x3);
                float depth = fmaxf(-pf4[j], 0.0f);
                float e   = fexp2(depth * cExp);
                float dip = fast_rcp(fmaf(e, 148.413159f, 1.0f));
                float fb  = fast_rcp(fmaf(e, 2.35385267e17f, 1.0f));
                dipA += dip;
                fbA  += fb;
            }
            if (isFirst && l < 4) {           // records 0..15 = positions < 0
#pragma unroll
                for (int j = 0; j < 8; ++j) dw[j] = 0u;
            }
            *(uint4*)&xs[8 * l]     = make_uint4(dw[0], dw[1], dw[2], dw[3]);
            *(uint4*)&xs[8 * l + 4] = make_uint4(dw[4], dw[5], dw[6], dw[7]);
            s_dip = fmaf(dipA, coreMask, s_dip);
            s_fb  = fmaf(fbA,  coreMask, s_fb);
        }

        // ======== stage B: conv1 (7x 32-wide + 16-wide tail) ========
        {
            const int cb = c + 2 * h + 5;
#pragma unroll 2
            for (int T = 0; T < 7; ++T) {
                const int R0 = 32 * T + cb;
                FragU b0, b1f;
                b0.u2[0]  = *(const uint2*)&xs[2 * R0];
                b0.u2[1]  = *(const uint2*)&xs[2 * R0 + 2];
                b1f.u2[0] = *(const uint2*)&xs[2 * R0 + 8];
                b1f.u2[1] = *(const uint2*)&xs[2 * R0 + 10];
                f32x16 d = __builtin_amdgcn_mfma_f32_32x32x16_bf16(a32_0, b0.v,  cb32, 0, 0, 0);
                d        = __builtin_amdgcn_mfma_f32_32x32x16_bf16(a32_1, b1f.v, d,    0, 0, 0);
                unsigned w0  = bfpack(fmaxf(d[0], 0.f), fmaxf(d[1], 0.f));
                unsigned w1_ = bfpack(fmaxf(d[2], 0.f), fmaxf(d[3], 0.f));
                if (isFirst && T == 0) {          // pos = c-8 < 0
                    if (c < 8) { w0 = 0u; w1_ = 0u; }
                }
                *(uint2*)&y1[4 * (32 * T + c) + 2 * h] = make_uint2(w0, w1_);
            }
            // tail: y1 records 224..239
            int qb = 224 + n + quad + 5;
            FragU bu;
            bu.u2[0] = *(const uint2*)&xs[2 * qb];
            bu.u2[1] = *(const uint2*)&xs[2 * (qb + 4)];
            f32x4 d = __builtin_amdgcn_mfma_f32_16x16x32_bf16(a1, bu.v, cb1, 0, 0, 0);
            if (l < 32) {
                unsigned w0  = bfpack(fmaxf(d[0], 0.f), fmaxf(d[1], 0.f));
                unsigned w1_ = bfpack(fmaxf(d[2], 0.f), fmaxf(d[3], 0.f));
                *(uint2*)&y1[4 * (224 + n) + 2 * quad] = make_uint2(w0, w1_);
            }
        }

        // ======== stage C: conv2, accumulate channel sums ========
#pragma unroll 2
        for (int t = 0; t < NTC; ++t) {
            int q = 16 * t + n + quad + 6;
            FragU u0, u1;
            u0.u4 = *(const uint4*)&y1[4 * q];
            u1.u4 = *(const uint4*)&y1[4 * (q + 4)];
            f32x4 d = __builtin_amdgcn_mfma_f32_16x16x32_bf16(a20, u0.v, cb2, 0, 0, 0);
            d = __builtin_amdgcn_mfma_f32_16x16x32_bf16(a21, u1.v, d, 0, 0, 0);
            m0 += fmaxf(d[0], 0.f);
            m1 += fmaxf(d[1], 0.f);
            m2 += fmaxf(d[2], 0.f);
            m3 += fmaxf(d[3], 0.f);
        }

        ph4 = nph; pf4 = npf; sf4 = nsf; oe4 = noe;
    }

    // ---- last chunk (ch = 8): scalar A, straddle-masked B, masked C ----
    {
        const int c0 = (NCH - 1) * CCH;       // 1792
        const int pb = c0 - 16;               // 1776

        // stage A: per-record valid/core
        {
            bool co0 = (l >= 16);
            int  p3  = pb + l + 192;
            bool v3  = (l < 33);              // p <= 2000
            bool co3 = v3 && (l < 48);
            if (p3 > 2000) p3 = 2000;
            aRec(l,        pb + l,       true, co0);
            aRec(l + 64,   pb + l + 64,  true, true);
            aRec(l + 128,  pb + l + 128, true, true);
            aRec(l + 192,  p3,           v3,   co3);
        }

        // stage B: 7 tiles; T==6 straddles pos 2000 (c>24 invalid)
        {
            const int cb = c + 2 * h + 5;
#pragma unroll 2
            for (int T = 0; T < 7; ++T) {
                const int R0 = 32 * T + cb;
                FragU b0, b1f;
                b0.u2[0]  = *(const uint2*)&xs[2 * R0];
                b0.u2[1]  = *(const uint2*)&xs[2 * R0 + 2];
                b1f.u2[0] = *(const uint2*)&xs[2 * R0 + 8];
                b1f.u2[1] = *(const uint2*)&xs[2 * R0 + 10];
                f32x16 d = __builtin_amdgcn_mfma_f32_32x32x16_bf16(a32_0, b0.v,  cb32, 0, 0, 0);
                d        = __builtin_amdgcn_mfma_f32_32x32x16_bf16(a32_1, b1f.v, d,    0, 0, 0);
                unsigned w0  = bfpack(fmaxf(d[0], 0.f), fmaxf(d[1], 0.f));
                unsigned w1_ = bfpack(fmaxf(d[2], 0.f), fmaxf(d[3], 0.f));
                if (T == 6 && c > 24) { w0 = 0u; w1_ = 0u; }   // pos = 1976+c > 2000
                *(uint2*)&y1[4 * (32 * T + c) + 2 * h] = make_uint2(w0, w1_);
            }
            // tail records 224..239: positions 2008..2023, all beyond row
            if (l < 32)
                *(uint2*)&y1[4 * (224 + n) + 2 * quad] = make_uint2(0u, 0u);
        }

        // stage C: tile 13 outputs 2000..2015 -> only n==0 valid
#pragma unroll 2
        for (int t = 0; t < NTC; ++t) {
            int q = 16 * t + n + quad + 6;
            FragU u0, u1;
            u0.u4 = *(const uint4*)&y1[4 * q];
            u1.u4 = *(const uint4*)&y1[4 * (q + 4)];
            f32x4 d = __builtin_amdgcn_mfma_f32_16x16x32_bf16(a20, u0.v, cb2, 0, 0, 0);
            d = __builtin_amdgcn_mfma_f32_16x16x32_bf16(a21, u1.v, d, 0, 0, 0);
            if (t == 13) {
                float msk = (n == 0) ? 1.0f : 0.0f;
                m0 = fmaf(fmaxf(d[0], 0.f), msk, m0);
                m1 = fmaf(fmaxf(d[1], 0.f), msk, m1);
                m2 = fmaf(fmaxf(d[2], 0.f), msk, m2);
                m3 = fmaf(fmaxf(d[3], 0.f), msk, m3);
            } else {
                m0 += fmaxf(d[0], 0.f);
                m1 += fmaxf(d[1], 0.f);
                m2 += fmaxf(d[2], 0.f);
                m3 += fmaxf(d[3], 0.f);
            }
        }
    }

    // ---- per-wave reductions (no LDS, no barriers) ----
#pragma unroll
    for (int dlt = 8; dlt >= 1; dlt >>= 1) {     // sum over n within 16-group
        m0 += __shfl_xor(m0, dlt);
        m1 += __shfl_xor(m1, dlt);
        m2 += __shfl_xor(m2, dlt);
        m3 += __shfl_xor(m3, dlt);
    }
    float part = m0 * fw0 + m1 * fw1 + m2 * fw2 + m3 * fw3;
    part = (n == 0) ? part : 0.0f;
    part += __shfl_xor(part, 16);
    part += __shfl_xor(part, 32);
#pragma unroll
    for (int dlt = 32; dlt >= 1; dlt >>= 1) {
        s_dip += __shfl_xor(s_dip, dlt);
        s_fb  += __shfl_xor(s_fb,  dlt);
        s_auc += __shfl_xor(s_auc, dlt);
    }

    if (l == 0) {
        float Sing = s_dip - s_fb;               // sum(ing) = sum(dip) - sum(fb)
        float logit = fcb[0] + part * (1.0f / 2001.0f);
        float auc_raw  = (float)(2.0 / 199.0) * s_auc;
        float auc_norm = auc_raw / A_abs;
        float m_ing = Sing / 2001.0f;
        float m_fb  = s_fb  / 2001.0f;
        float t14   = s_dip / 2001.0f + 1e-8f;   // (Sing+Sfb) == Sdip
        float t12   = m_ing / t14;

        logit += Bp       * fcw[16]
               + auc_raw  * fcw[17]
               + auc_norm * fcw[18]
               + t12      * fcw[19]
               + m_fb     * fcw[20];

        out[row] = 1.0f / (1.0f + expf(-logit));
    }
}

extern "C" void kernel_launch(void* const* d_in, const int* in_sizes, int n_in,
                              void* d_out, int out_size, void* d_ws, size_t ws_size,
                              hipStream_t stream) {
    const float* phase     = (const float*)d_in[0];
    const float* primary   = (const float*)d_in[1];
    const float* secondary = (const float*)d_in[2];
    const float* oddeven   = (const float*)d_in[3];
    const float* pA        = (const float*)d_in[4];
    const float* pBp       = (const float*)d_in[5];
    const float* pT0       = (const float*)d_in[6];
    const float* bng       = (const float*)d_in[7];
    const float* bnb       = (const float*)d_in[8];
    const float* bnm       = (const float*)d_in[9];
    const float* bnv       = (const float*)d_in[10];
    const float* w1        = (const float*)d_in[11];
    const float* b1        = (const float*)d_in[12];
    const float* w2        = (const float*)d_in[13];
    const float* b2        = (const float*)d_in[14];
    const float* fcw       = (const float*)d_in[15];
    const float* fcb       = (const float*)d_in[16];
    float* out = (float*)d_out;

    int nrows = in_sizes[0] / L_LEN;   // 8192
    dim3 grid((nrows + 3) / 4), block(256);
    hipLaunchKernelGGL(taylor_cnn_v11_wave, grid, block, 0, stream,
                       phase, primary, secondary, oddeven, pA, pBp, pT0,
                       bng, bnb, bnm, bnv, w1, b1, w2, b2, fcw, fcb, out, nrows);
}

// Round 6
// 278.061 us; speedup vs baseline: 1.1525x; 1.0138x over previous
//
#include <hip/hip_runtime.h>
#include <math.h>

#define L_LEN 2001
#define CCH 224           // positions per chunk per wave
#define NCH 9             // chunks: 9*224 = 2016 >= 2001
#define XRECS 256         // xs records per chunk (CCH+32) -> exactly 4 per lane
#define YRECS 240         // y1 records per chunk (CCH+16)
#define NTC 14            // conv2 tiles per chunk (CCH/16 outputs)

typedef __attribute__((ext_vector_type(8))) short bf16x8;
typedef __attribute__((ext_vector_type(4))) float f32x4;
typedef __attribute__((ext_vector_type(16))) float f32x16;
typedef __attribute__((ext_vector_type(4), aligned(4))) float f32x4u;  // unaligned-tolerant
#if __has_builtin(__builtin_amdgcn_cvt_pk_bf16_f32)
typedef __attribute__((ext_vector_type(2))) __bf16 bf16x2_t;
#endif

union FragU { unsigned u[4]; uint2 u2[2]; uint4 u4; bf16x8 v; };

__device__ __forceinline__ unsigned short f2bf(float f) {
    unsigned u = __builtin_bit_cast(unsigned, f);
    u += 0x7fffu + ((u >> 16) & 1u);
    return (unsigned short)(u >> 16);
}
// pack two fp32 -> bf16 pair (RNE), hi<<16 | lo
__device__ __forceinline__ unsigned bfpack(float lo, float hi) {
#if __has_builtin(__builtin_amdgcn_cvt_pk_bf16_f32)
    bf16x2_t r = __builtin_amdgcn_cvt_pk_bf16_f32(lo, hi);   // S0 -> [15:0]
    return __builtin_bit_cast(unsigned, r);
#else
    unsigned ul = __builtin_bit_cast(unsigned, lo);
    unsigned uh = __builtin_bit_cast(unsigned, hi);
    ul += 0x7fffu + ((ul >> 16) & 1u);
    uh += 0x7fffu + ((uh >> 16) & 1u);
    return __builtin_amdgcn_perm(uh, ul, 0x07060302);
#endif
}
__device__ __forceinline__ float fast_rcp(float x) { return __builtin_amdgcn_rcpf(x); }
__device__ __forceinline__ float fexp2(float x) {
#if __has_builtin(__builtin_amdgcn_exp2f)
    return __builtin_amdgcn_exp2f(x);
#else
    return __expf(x * 0.69314718f);
#endif
}

// Wave-per-row, zero barriers (R3); 32x32 conv1 + vectorized stage A (R4);
// T14 register prefetch (R5). R6: launch_bounds (256,4)->(256,3) -- the
// prefetch's +16 live regs overflowed the 128-reg unified cap and spilled
// ~12 MB/dispatch of scratch (R5 WRITE_SIZE). Cap ~170 fits it; 3 waves/EU
// is what we measure resident anyway, so no occupancy loss.
__global__ __launch_bounds__(256, 3)
void taylor_cnn_v11_wave(const float* __restrict__ phase, const float* __restrict__ primary,
                         const float* __restrict__ secondary, const float* __restrict__ oddeven,
                         const float* __restrict__ pA, const float* __restrict__ pBp,
                         const float* __restrict__ pT0,
                         const float* __restrict__ bng, const float* __restrict__ bnb,
                         const float* __restrict__ bnm, const float* __restrict__ bnv,
                         const float* __restrict__ w1, const float* __restrict__ b1,
                         const float* __restrict__ w2, const float* __restrict__ b2,
                         const float* __restrict__ fcw, const float* __restrict__ fcb,
                         float* __restrict__ out, int nrows)
{
    // per-wave LDS slices (no cross-wave sharing, no barriers)
    __shared__ __align__(16) unsigned int xs_i[4][XRECS * 2];   // 8.0 KB
    __shared__ __align__(16) unsigned int y1_i[4][YRECS * 4];   // 15.4 KB

    const int tid = threadIdx.x;
    const int l   = tid & 63;
    const int wid = tid >> 6;
    const int row = blockIdx.x * 4 + wid;
    if (row >= nrows) return;                 // wave-uniform; legal (no barriers)
    const long base = (long)row * L_LEN;

    unsigned int* xs = xs_i[wid];
    unsigned int* y1 = y1_i[wid];

    const int n    = l & 15;     // 16x16 MFMA column (conv2 / tail tile)
    const int quad = l >> 4;     // 16x16 MFMA k-block / D row-quad
    const int c    = l & 31;     // 32x32 MFMA column (conv1)
    const int h    = l >> 5;     // 32x32 MFMA half

    const float A  = pA[0];
    const float Bp = pBp[0];
    const float t0 = pT0[0];
    const float A_abs = fabsf(A) + 1e-8f;
    const float rAabs = 1.0f / A_abs;
    const float nBp  = -Bp;
    const float cExp = -72.134766f * rAabs;   // -50*log2(e)*rAabs: exp(-50*dn)=exp2(cExp*depth)

    float inv1, inv2, inv3, gInv0, off0, off1, off2, off3;
    {
        float iv0 = bng[0] / sqrtf(bnv[0] + 1e-5f);
        float iv1 = bng[1] / sqrtf(bnv[1] + 1e-5f);
        float iv2 = bng[2] / sqrtf(bnv[2] + 1e-5f);
        float iv3 = bng[3] / sqrtf(bnv[3] + 1e-5f);
        gInv0 = -A * iv0;                     // gate = relu(1-Bp*d^2); x0 = gate*(-A*iv0)+off0
        inv1 = iv1; inv2 = iv2; inv3 = iv3;
        off0 = bnb[0] - bnm[0] * iv0;
        off1 = bnb[1] - bnm[1] * iv1;
        off2 = bnb[2] - bnm[2] * iv2;
        off3 = bnb[3] - bnm[3] * iv3;
    }

    // ---- conv1 32x32x16 A-fragments: row = l&31 (oc), k = 8*h + j ----
    //   MFMA0: (ch = j&3, tap = (j>>2) + 2h)       taps 0..3
    //   MFMA1: (ch = j&3, tap = 4 + (j>>2) + 2h)   taps 4..6 (tap7 -> 0)
    bf16x8 a32_0, a32_1;
#pragma unroll
    for (int jp = 0; jp < 8; ++jp) {
        int ch_  = jp & 3;
        int tap0 = (jp >> 2) + 2 * h;
        int tap1 = 4 + (jp >> 2) + 2 * h;
        float v0 = (c < 8) ? w1[(c * 4 + ch_) * 7 + tap0] : 0.0f;
        float v1 = (c < 8 && tap1 < 7) ? w1[(c * 4 + ch_) * 7 + tap1] : 0.0f;
        a32_0[jp] = (short)f2bf(v0);
        a32_1[jp] = (short)f2bf(v1);
    }
    // conv1 bias in C operand: D reg r<4 -> row (r&3)+4h
    f32x16 cb32;
#pragma unroll
    for (int r = 0; r < 16; ++r)
        cb32[r] = (r < 4) ? b1[(r & 3) + 4 * h] : 0.0f;

    // ---- old 16x16x32 conv1 fragment (tail tile, records 224..239) ----
    bf16x8 a1;
#pragma unroll
    for (int jp = 0; jp < 8; ++jp) {
        int j = quad + 4 * (jp >> 2);
        int cc = jp & 3;
        float v = (n < 8 && j < 7) ? w1[(n * 4 + cc) * 7 + j] : 0.0f;
        a1[jp] = (short)f2bf(v);
    }
    // ---- conv2 fragments (unchanged) ----
    bf16x8 a20, a21;
#pragma unroll
    for (int jp = 0; jp < 8; ++jp) {
        float v0 = w2[(n * 8 + jp) * 5 + quad];
        float v1 = (quad + 4 < 5) ? w2[(n * 8 + jp) * 5 + quad + 4] : 0.0f;
        a20[jp] = (short)f2bf(v0);
        a21[jp] = (short)f2bf(v1);
    }
    f32x4 cb1, cb2;
#pragma unroll
    for (int r = 0; r < 4; ++r) {
        cb1[r] = b1[(quad * 4 + r) & 7];
        cb2[r] = b2[quad * 4 + r];
    }
    // fc weights for the CNN means (per-lane quad's 4 oc)
    float fw0 = fcw[quad * 4 + 0];
    float fw1 = fcw[quad * 4 + 1];
    float fw2 = fcw[quad * 4 + 2];
    float fw3 = fcw[quad * 4 + 3];

    float s_dip = 0.0f, s_fb = 0.0f;          // sum(dip), sum(fb); ing = dip-fb folded out
    float m0 = 0.f, m1 = 0.f, m2 = 0.f, m3 = 0.f;

    // trapz AUC: 200 samples per row -> 4 per lane (last masked to l<8)
    float s_auc = 0.0f;
#pragma unroll
    for (int k = 0; k < 4; ++k) {
        int s = l + 64 * k;
        if (k < 3 || l < 8) {
            float pos = (float)s * (2000.0f / 199.0f);
            int i0 = (int)pos;
            if (i0 > 2000) i0 = 2000;
            int i1 = (i0 + 1 < L_LEN) ? i0 + 1 : 2000;
            float w  = pos - (float)i0;
            float d0 = fmaxf(-primary[base + i0], 0.f);
            float d1 = fmaxf(-primary[base + i1], 0.f);
            float v  = d0 * (1.0f - w) + d1 * w;
            float wt = (s == 0 || s == 199) ? 0.5f : 1.0f;
            s_auc += v * wt;
        }
    }

    // ---- stage A scalar record processor (last chunk only) ----
    auto aRec = [&](int m, int p, bool valid, bool core) {
        float ph = phase[base + p];
        float pf = primary[base + p];
        float sf = secondary[base + p];
        float oe = oddeven[base + p];
        float dd = ph - t0;
        float g  = fmaxf(fmaf(dd * dd, nBp, 1.0f), 0.0f);
        float x0 = fmaf(g,  gInv0, off0);
        float x1 = fmaf(pf, inv1, off1);
        float x2 = fmaf(sf, inv2, off2);
        float x3 = fmaf(oe, inv3, off3);
        unsigned d0 = bfpack(x0, x1);
        unsigned d1 = bfpack(x2, x3);
        if (!valid) { d0 = 0u; d1 = 0u; }
        *(uint2*)&xs[2 * m] = make_uint2(d0, d1);
        float depth = fmaxf(-pf, 0.0f);
        float e   = fexp2(depth * cExp);
        float dip = fast_rcp(fmaf(e, 148.413159f, 1.0f));
        float fb  = fast_rcp(fmaf(e, 2.35385267e17f, 1.0f));
        if (!core) { dip = 0.f; fb = 0.f; }
        s_dip += dip;
        s_fb  += fb;
    };

    const float coreMask = (l >= 4 && l < 60) ? 1.0f : 0.0f;   // records 16..239

    // ---- T14 prefetch: preload chunk 0 ----
    f32x4u ph4, pf4, sf4, oe4;
    {
        int p0 = 4 * l - 16; if (p0 < 0) p0 = 0;
        ph4 = *(const f32x4u*)&phase[base + p0];
        pf4 = *(const f32x4u*)&primary[base + p0];
        sf4 = *(const f32x4u*)&secondary[base + p0];
        oe4 = *(const f32x4u*)&oddeven[base + p0];
    }

    // ---- vector chunks 0..7: A | B | C, wave-synchronous ----
#pragma unroll 1
    for (int ch = 0; ch < NCH - 1; ++ch) {
        const int c0 = ch * CCH;
        const bool isFirst = (ch == 0);

        // issue NEXT chunk's loads now; waitcnt lands at next iteration's
        // stage A, i.e. latency hides under this chunk's B+C
        f32x4u nph, npf, nsf, noe;
        if (ch < NCH - 2) {
            const long pn = base + (c0 + CCH - 16 + 4 * l);
            nph = *(const f32x4u*)&phase[pn];
            npf = *(const f32x4u*)&primary[pn];
            nsf = *(const f32x4u*)&secondary[pn];
            noe = *(const f32x4u*)&oddeven[pn];
        } else {
            nph = ph4; npf = pf4; nsf = sf4; noe = oe4;   // dead
        }

        // ======== stage A (from prefetched regs) ========
        {
            unsigned dw[8];
            float dipA = 0.f, fbA = 0.f;
#pragma unroll
            for (int j = 0; j < 4; ++j) {
                float dd = ph4[j] - t0;
                float g  = fmaxf(fmaf(dd * dd, nBp, 1.0f), 0.0f);
                float x0 = fmaf(g,      gInv0, off0);
                float x1 = fmaf(pf4[j], inv1,  off1);
                float x2 = fmaf(sf4[j], inv2,  off2);
                float x3 = fmaf(oe4[j], inv3,  off3);
                dw[2 * j]     = bfpack(x0, x1);
                dw[2 * j + 1] = bfpack(x2, x3);
                float depth = fmaxf(-pf4[j], 0.0f);
                float e   = fexp2(depth * cExp);
                float dip = fast_rcp(fmaf(e, 148.413159f, 1.0f));
                float fb  = fast_rcp(fmaf(e, 2.35385267e17f, 1.0f));
                dipA += dip;
                fbA  += fb;
            }
            if (isFirst && l < 4) {           // records 0..15 = positions < 0
#pragma unroll
                for (int j = 0; j < 8; ++j) dw[j] = 0u;
            }
            *(uint4*)&xs[8 * l]     = make_uint4(dw[0], dw[1], dw[2], dw[3]);
            *(uint4*)&xs[8 * l + 4] = make_uint4(dw[4], dw[5], dw[6], dw[7]);
            s_dip = fmaf(dipA, coreMask, s_dip);
            s_fb  = fmaf(fbA,  coreMask, s_fb);
        }

        // ======== stage B: conv1 (7x 32-wide + 16-wide tail) ========
        {
            const int cb = c + 2 * h + 5;
#pragma unroll 2
            for (int T = 0; T < 7; ++T) {
                const int R0 = 32 * T + cb;
                FragU b0, b1f;
                b0.u2[0]  = *(const uint2*)&xs[2 * R0];
                b0.u2[1]  = *(const uint2*)&xs[2 * R0 + 2];
                b1f.u2[0] = *(const uint2*)&xs[2 * R0 + 8];
                b1f.u2[1] = *(const uint2*)&xs[2 * R0 + 10];
                f32x16 d = __builtin_amdgcn_mfma_f32_32x32x16_bf16(a32_0, b0.v,  cb32, 0, 0, 0);
                d        = __builtin_amdgcn_mfma_f32_32x32x16_bf16(a32_1, b1f.v, d,    0, 0, 0);
                unsigned w0  = bfpack(fmaxf(d[0], 0.f), fmaxf(d[1], 0.f));
                unsigned w1_ = bfpack(fmaxf(d[2], 0.f), fmaxf(d[3], 0.f));
                if (isFirst && T == 0) {          // pos = c-8 < 0
                    if (c < 8) { w0 = 0u; w1_ = 0u; }
                }
                *(uint2*)&y1[4 * (32 * T + c) + 2 * h] = make_uint2(w0, w1_);
            }
            // tail: y1 records 224..239
            int qb = 224 + n + quad + 5;
            FragU bu;
            bu.u2[0] = *(const uint2*)&xs[2 * qb];
            bu.u2[1] = *(const uint2*)&xs[2 * (qb + 4)];
            f32x4 d = __builtin_amdgcn_mfma_f32_16x16x32_bf16(a1, bu.v, cb1, 0, 0, 0);
            if (l < 32) {
                unsigned w0  = bfpack(fmaxf(d[0], 0.f), fmaxf(d[1], 0.f));
                unsigned w1_ = bfpack(fmaxf(d[2], 0.f), fmaxf(d[3], 0.f));
                *(uint2*)&y1[4 * (224 + n) + 2 * quad] = make_uint2(w0, w1_);
            }
        }

        // ======== stage C: conv2, accumulate channel sums ========
#pragma unroll 2
        for (int t = 0; t < NTC; ++t) {
            int q = 16 * t + n + quad + 6;
            FragU u0, u1;
            u0.u4 = *(const uint4*)&y1[4 * q];
            u1.u4 = *(const uint4*)&y1[4 * (q + 4)];
            f32x4 d = __builtin_amdgcn_mfma_f32_16x16x32_bf16(a20, u0.v, cb2, 0, 0, 0);
            d = __builtin_amdgcn_mfma_f32_16x16x32_bf16(a21, u1.v, d, 0, 0, 0);
            m0 += fmaxf(d[0], 0.f);
            m1 += fmaxf(d[1], 0.f);
            m2 += fmaxf(d[2], 0.f);
            m3 += fmaxf(d[3], 0.f);
        }

        ph4 = nph; pf4 = npf; sf4 = nsf; oe4 = noe;
    }

    // ---- last chunk (ch = 8): scalar A, straddle-masked B, masked C ----
    {
        const int c0 = (NCH - 1) * CCH;       // 1792
        const int pb = c0 - 16;               // 1776

        // stage A: per-record valid/core
        {
            bool co0 = (l >= 16);
            int  p3  = pb + l + 192;
            bool v3  = (l < 33);              // p <= 2000
            bool co3 = v3 && (l < 48);
            if (p3 > 2000) p3 = 2000;
            aRec(l,        pb + l,       true, co0);
            aRec(l + 64,   pb + l + 64,  true, true);
            aRec(l + 128,  pb + l + 128, true, true);
            aRec(l + 192,  p3,           v3,   co3);
        }

        // stage B: 7 tiles; T==6 straddles pos 2000 (c>24 invalid)
        {
            const int cb = c + 2 * h + 5;
#pragma unroll 2
            for (int T = 0; T < 7; ++T) {
                const int R0 = 32 * T + cb;
                FragU b0, b1f;
                b0.u2[0]  = *(const uint2*)&xs[2 * R0];
                b0.u2[1]  = *(const uint2*)&xs[2 * R0 + 2];
                b1f.u2[0] = *(const uint2*)&xs[2 * R0 + 8];
                b1f.u2[1] = *(const uint2*)&xs[2 * R0 + 10];
                f32x16 d = __builtin_amdgcn_mfma_f32_32x32x16_bf16(a32_0, b0.v,  cb32, 0, 0, 0);
                d        = __builtin_amdgcn_mfma_f32_32x32x16_bf16(a32_1, b1f.v, d,    0, 0, 0);
                unsigned w0  = bfpack(fmaxf(d[0], 0.f), fmaxf(d[1], 0.f));
                unsigned w1_ = bfpack(fmaxf(d[2], 0.f), fmaxf(d[3], 0.f));
                if (T == 6 && c > 24) { w0 = 0u; w1_ = 0u; }   // pos = 1976+c > 2000
                *(uint2*)&y1[4 * (32 * T + c) + 2 * h] = make_uint2(w0, w1_);
            }
            // tail records 224..239: positions 2008..2023, all beyond row
            if (l < 32)
                *(uint2*)&y1[4 * (224 + n) + 2 * quad] = make_uint2(0u, 0u);
        }

        // stage C: tile 13 outputs 2000..2015 -> only n==0 valid
#pragma unroll 2
        for (int t = 0; t < NTC; ++t) {
            int q = 16 * t + n + quad + 6;
            FragU u0, u1;
            u0.u4 = *(const uint4*)&y1[4 * q];
            u1.u4 = *(const uint4*)&y1[4 * (q + 4)];
            f32x4 d = __builtin_amdgcn_mfma_f32_16x16x32_bf16(a20, u0.v, cb2, 0, 0, 0);
            d = __builtin_amdgcn_mfma_f32_16x16x32_bf16(a21, u1.v, d, 0, 0, 0);
            if (t == 13) {
                float msk = (n == 0) ? 1.0f : 0.0f;
                m0 = fmaf(fmaxf(d[0], 0.f), msk, m0);
                m1 = fmaf(fmaxf(d[1], 0.f), msk, m1);
                m2 = fmaf(fmaxf(d[2], 0.f), msk, m2);
                m3 = fmaf(fmaxf(d[3], 0.f), msk, m3);
            } else {
                m0 += fmaxf(d[0], 0.f);
                m1 += fmaxf(d[1], 0.f);
                m2 += fmaxf(d[2], 0.f);
                m3 += fmaxf(d[3], 0.f);
            }
        }
    }

    // ---- per-wave reductions (no LDS, no barriers) ----
#pragma unroll
    for (int dlt = 8; dlt >= 1; dlt >>= 1) {     // sum over n within 16-group
        m0 += __shfl_xor(m0, dlt);
        m1 += __shfl_xor(m1, dlt);
        m2 += __shfl_xor(m2, dlt);
        m3 += __shfl_xor(m3, dlt);
    }
    float part = m0 * fw0 + m1 * fw1 + m2 * fw2 + m3 * fw3;
    part = (n == 0) ? part : 0.0f;
    part += __shfl_xor(part, 16);
    part += __shfl_xor(part, 32);
#pragma unroll
    for (int dlt = 32; dlt >= 1; dlt >>= 1) {
        s_dip += __shfl_xor(s_dip, dlt);
        s_fb  += __shfl_xor(s_fb,  dlt);
        s_auc += __shfl_xor(s_auc, dlt);
    }

    if (l == 0) {
        float Sing = s_dip - s_fb;               // sum(ing) = sum(dip) - sum(fb)
        float logit = fcb[0] + part * (1.0f / 2001.0f);
        float auc_raw  = (float)(2.0 / 199.0) * s_auc;
        float auc_norm = auc_raw / A_abs;
        float m_ing = Sing / 2001.0f;
        float m_fb  = s_fb  / 2001.0f;
        float t14   = s_dip / 2001.0f + 1e-8f;   // (Sing+Sfb) == Sdip
        float t12   = m_ing / t14;

        logit += Bp       * fcw[16]
               + auc_raw  * fcw[17]
               + auc_norm * fcw[18]
               + t12      * fcw[19]
               + m_fb     * fcw[20];

        out[row] = 1.0f / (1.0f + expf(-logit));
    }
}

extern "C" void kernel_launch(void* const* d_in, const int* in_sizes, int n_in,
                              void* d_out, int out_size, void* d_ws, size_t ws_size,
                              hipStream_t stream) {
    const float* phase     = (const float*)d_in[0];
    const float* primary   = (const float*)d_in[1];
    const float* secondary = (const float*)d_in[2];
    const float* oddeven   = (const float*)d_in[3];
    const float* pA        = (const float*)d_in[4];
    const float* pBp       = (const float*)d_in[5];
    const float* pT0       = (const float*)d_in[6];
    const float* bng       = (const float*)d_in[7];
    const float* bnb       = (const float*)d_in[8];
    const float* bnm       = (const float*)d_in[9];
    const float* bnv       = (const float*)d_in[10];
    const float* w1        = (const float*)d_in[11];
    const float* b1        = (const float*)d_in[12];
    const float* w2        = (const float*)d_in[13];
    const float* b2        = (const float*)d_in[14];
    const float* fcw       = (const float*)d_in[15];
    const float* fcb       = (const float*)d_in[16];
    float* out = (float*)d_out;

    int nrows = in_sizes[0] / L_LEN;   // 8192
    dim3 grid((nrows + 3) / 4), block(256);
    hipLaunchKernelGGL(taylor_cnn_v11_wave, grid, block, 0, stream,
                       phase, primary, secondary, oddeven, pA, pBp, pT0,
                       bng, bnb, bnm, bnv, w1, b1, w2, b2, fcw, fcb, out, nrows);
}